// Round 1
// baseline (176.125 us; speedup 1.0000x reference)
//
#include <hip/hip_runtime.h>
#include <hip/hip_bf16.h>
#include <stdint.h>

// Problem constants (fixed by the reference)
#define NQ    32768
#define NKV   32768
#define CDIM  256
#define NHEADS 8
#define NPTS  4
// Ch = 32, pairs (h,p) = 32, loc cols used = even cols only (x coord)

using bf16x8 = __attribute__((ext_vector_type(8))) short;
using f32x4  = __attribute__((ext_vector_type(4))) float;

static __device__ __forceinline__ ushort f2bf(float f) {
  uint32_t u = __float_as_uint(f);
  return (ushort)((u + 0x7FFFu + ((u >> 16) & 1u)) >> 16);  // RNE
}
static __device__ __forceinline__ float bf2f(ushort h) {
  return __uint_as_float(((uint32_t)h) << 16);
}
static __device__ __forceinline__ void async16(const void* g, void* l) {
  __builtin_amdgcn_global_load_lds(
      (const __attribute__((address_space(1))) uint32_t*)g,
      (__attribute__((address_space(3))) uint32_t*)l, 16, 0, 0);
}

// ---------------------------------------------------------------------------
// K0a: value f32 -> bf16 (row-major, same layout). 4 floats/thread.
__global__ __launch_bounds__(256) void convert_val(const float* __restrict__ V,
                                                   ushort* __restrict__ O) {
  int i = blockIdx.x * 256 + threadIdx.x;
  float4 v = *(const float4*)&V[(size_t)i * 4];
  ushort4 o;
  o.x = f2bf(v.x); o.y = f2bf(v.y); o.z = f2bf(v.z); o.w = f2bf(v.w);
  *(ushort4*)&O[(size_t)i * 4] = o;
}

// K0b: W [256][256] f32 -> W^T [256][256] bf16 (row j holds column j of W,
// k-contiguous — the layout the MFMA B-operand wants).
__global__ __launch_bounds__(256) void transpose_w(const float* __restrict__ W,
                                                   ushort* __restrict__ WT) {
  int j = blockIdx.x, k = threadIdx.x;
  WT[j * 256 + k] = f2bf(W[k * 256 + j]);
}

// ---------------------------------------------------------------------------
// K1/K3: bf16 MFMA GEMM  C[M,256] = A[M,256] * B + bias
//  A row-major bf16, BT = B^T row-major bf16. 128x128 tile, BK=32,
//  256 threads = 4 waves in 2x2, each wave 4x4 frags of 16x16x32.
__global__ __launch_bounds__(256) void gemm_mfma(
    const ushort* __restrict__ A, const ushort* __restrict__ BT,
    const float* __restrict__ bias, ushort* __restrict__ Cb,
    float* __restrict__ Cf, int out_bf16) {
  __shared__ ushort Alds[128 * 32];
  __shared__ ushort Blds[128 * 32];
  const int t = threadIdx.x;
  const int wave = t >> 6, lane = t & 63;
  const int mt = blockIdx.x >> 1, nt = blockIdx.x & 1;
  const int m0 = mt * 128, n0 = nt * 128;
  const int wr = wave >> 1, wc = wave & 1;
  const int r16 = lane & 15, kb = (lane >> 4) * 8;

  f32x4 acc[4][4] = {};

  for (int kt = 0; kt < 256; kt += 32) {
    __syncthreads();  // previous iter's frag reads done before overwrite
#pragma unroll
    for (int it = 0; it < 2; ++it) {
      int c = it * 256 + t;           // 16B chunk id: row = c>>2, sub = c&3
      int row = c >> 2, cc = c & 3;
      // dest base is wave-uniform; HW adds lane*16
      async16(A  + ((size_t)(m0 + row) * 256 + kt + cc * 8),
              Alds + (size_t)(it * 256 + wave * 64) * 8);
      async16(BT + ((size_t)(n0 + row) * 256 + kt + cc * 8),
              Blds + (size_t)(it * 256 + wave * 64) * 8);
    }
    __syncthreads();  // drains vmcnt -> staged data visible

    bf16x8 af[4], bfr[4];
#pragma unroll
    for (int m = 0; m < 4; ++m)
      af[m] = *(const bf16x8*)&Alds[(wr * 64 + m * 16 + r16) * 32 + kb];
#pragma unroll
    for (int n = 0; n < 4; ++n)
      bfr[n] = *(const bf16x8*)&Blds[(wc * 64 + n * 16 + r16) * 32 + kb];
#pragma unroll
    for (int m = 0; m < 4; ++m)
#pragma unroll
      for (int n = 0; n < 4; ++n)
        acc[m][n] = __builtin_amdgcn_mfma_f32_16x16x32_bf16(af[m], bfr[n],
                                                            acc[m][n], 0, 0, 0);
  }

  const int rg = lane >> 4;
#pragma unroll
  for (int m = 0; m < 4; ++m)
#pragma unroll
    for (int n = 0; n < 4; ++n) {
      int gc = n0 + wc * 64 + n * 16 + r16;
      float bb = bias[gc];
#pragma unroll
      for (int r = 0; r < 4; ++r) {
        int gr = m0 + wr * 64 + m * 16 + rg * 4 + r;
        float v = acc[m][n][r] + bb;
        if (out_bf16) Cb[(size_t)gr * 256 + gc] = f2bf(v);
        else          Cf[(size_t)gr * 256 + gc] = v;
      }
    }
}

// ---------------------------------------------------------------------------
// K2a: loc_raw[N,64] = query @ [Wr_even | Wo_even]   (fp32 — score path
// must be fp32-exact; bf16 here would flip sharp softmaxes at |x|~1e5).
// 64x64 tile, 256 threads, 4x4 regs/thread, BK=64, A staged transposed.
__global__ __launch_bounds__(256) void loc_gemm(const float* __restrict__ Q,
                                                const float* __restrict__ Wr,
                                                const float* __restrict__ Wo,
                                                float* __restrict__ locr) {
  __shared__ float AT[64][68];  // [k][m], pad 68 keeps 16B align + banks spread
  __shared__ float Bl[64][64];  // [k][j]
  const int m0 = blockIdx.x * 64;
  const int t = threadIdx.x;
  const int tr = t >> 4, tc = t & 15;
  float acc[4][4] = {};

  for (int k0 = 0; k0 < 256; k0 += 64) {
    __syncthreads();
#pragma unroll
    for (int i = 0; i < 4; ++i) {  // A: 64 rows x 64 k, stored transposed
      int row = (t >> 4) + 16 * i;
      int kk = (t & 15) * 4;
      float4 v = *(const float4*)&Q[(size_t)(m0 + row) * 256 + k0 + kk];
      AT[kk + 0][row] = v.x; AT[kk + 1][row] = v.y;
      AT[kk + 2][row] = v.z; AT[kk + 3][row] = v.w;
    }
#pragma unroll
    for (int i = 0; i < 16; ++i) { // B: even cols of Wr (j<32) / Wo (j>=32)
      int j = t & 63;
      int kk = (t >> 6) + 4 * i;
      float v = (j < 32) ? Wr[(size_t)(k0 + kk) * 64 + 2 * j]
                         : Wo[(size_t)(k0 + kk) * 64 + 2 * (j - 32)];
      Bl[kk][j] = v;
    }
    __syncthreads();
#pragma unroll 8
    for (int kk = 0; kk < 64; ++kk) {
      float4 a = *(const float4*)&AT[kk][tr * 4];
      float4 b = *(const float4*)&Bl[kk][tc * 4];
      float av[4] = {a.x, a.y, a.z, a.w};
      float bv4[4] = {b.x, b.y, b.z, b.w};
#pragma unroll
      for (int i = 0; i < 4; ++i)
#pragma unroll
        for (int jj = 0; jj < 4; ++jj) acc[i][jj] += av[i] * bv4[jj];
    }
  }
#pragma unroll
  for (int i = 0; i < 4; ++i)
#pragma unroll
    for (int jj = 0; jj < 4; ++jj)
      locr[(size_t)(m0 + tr * 4 + i) * 64 + tc * 4 + jj] = acc[i][jj];
}

// ---------------------------------------------------------------------------
// K2b: fused sampling + scores + softmax + weighted sum.
// One wave per query row. lane = c (0..31) x {x0-side, x1-side}.
// Scores fully fp32 (key gathered f32); values gathered from bf16 vtab.
__global__ __launch_bounds__(256) void sample_attn(
    const float* __restrict__ query, const float* __restrict__ key,
    const ushort* __restrict__ vtab, const float* __restrict__ locr,
    const float* __restrict__ br, const float* __restrict__ bo,
    ushort* __restrict__ out2) {
  const int wave = threadIdx.x >> 6, lane = threadIdx.x & 63;
  const int n = blockIdx.x * 4 + wave;
  const int j = lane & 31;   // pair index for loc; channel index for math
  const int half = lane >> 5;
  const int Mm1 = NKV - 1;

  // loc for pair j (both halves compute identically)
  float rr = locr[(size_t)n * 64 + j];
  float oo = locr[(size_t)n * 64 + 32 + j];
  float ref = 1.0f / (1.0f + expf(-(rr + br[2 * j])));
  float x = (ref + (oo + bo[2 * j])) * (float)Mm1;
  float xf = floorf(x);
  int x0 = (int)fminf(fmaxf(xf, 0.0f), (float)Mm1);
  int x1 = (x0 + 1 > Mm1) ? Mm1 : x0 + 1;
  float wx = x - (float)x0;

  const int c = j;
  for (int h = 0; h < NHEADS; ++h) {
    float qc = query[(size_t)n * 256 + h * 32 + c];
    float sc[4], sv[4];
#pragma unroll
    for (int p = 0; p < 4; ++p) {
      int jp = h * 4 + p;
      int xx0 = __shfl(x0, jp, 64);
      int xx1 = __shfl(x1, jp, 64);
      float wxx = __shfl(wx, jp, 64);
      int src = half ? xx1 : xx0;
      size_t base = (size_t)src * 256 + h * 32 + c;
      float kv = key[base];
      float vv = bf2f(vtab[base]);
      float kv1 = __shfl(kv, (lane & 31) + 32, 64);  // partner (x1) value
      float vv1 = __shfl(vv, (lane & 31) + 32, 64);
      float sk = (1.0f - wxx) * kv + wxx * kv1;      // valid on lanes<32
      sv[p] = (1.0f - wxx) * vv + wxx * vv1;
      float ts = qc * sk;                            // 32-ch dot, lower half
      ts += __shfl_xor(ts, 1, 64);
      ts += __shfl_xor(ts, 2, 64);
      ts += __shfl_xor(ts, 4, 64);
      ts += __shfl_xor(ts, 8, 64);
      ts += __shfl_xor(ts, 16, 64);
      sc[p] = ts * 0.17677669529663687f;             // 1/sqrt(32)
    }
    float mx = fmaxf(fmaxf(sc[0], sc[1]), fmaxf(sc[2], sc[3]));
    float e0 = expf(sc[0] - mx), e1 = expf(sc[1] - mx);
    float e2 = expf(sc[2] - mx), e3 = expf(sc[3] - mx);
    float inv = 1.0f / (e0 + e1 + e2 + e3);
    float o = (e0 * sv[0] + e1 * sv[1] + e2 * sv[2] + e3 * sv[3]) * inv;
    if (half == 0) out2[(size_t)n * 256 + h * 32 + c] = f2bf(o);
  }
}

// ---------------------------------------------------------------------------
extern "C" void kernel_launch(void* const* d_in, const int* in_sizes, int n_in,
                              void* d_out, int out_size, void* d_ws, size_t ws_size,
                              hipStream_t stream) {
  const float* query = (const float*)d_in[0];
  const float* key   = (const float*)d_in[1];
  const float* value = (const float*)d_in[2];
  const float* Wr    = (const float*)d_in[3];
  const float* br    = (const float*)d_in[4];
  const float* Wo    = (const float*)d_in[5];
  const float* bo    = (const float*)d_in[6];
  const float* Wv    = (const float*)d_in[7];
  const float* bv    = (const float*)d_in[8];
  const float* Wout  = (const float*)d_in[9];
  const float* bout  = (const float*)d_in[10];
  float* out = (float*)d_out;

  char* ws = (char*)d_ws;
  // val16 (16MB) is dead after the Wv GEMM; out2 reuses its space.
  ushort* val16 = (ushort*)(ws);                         // 16 MB
  ushort* out2  = (ushort*)(ws);                         // 16 MB (alias, later)
  ushort* vtab  = (ushort*)(ws + (16u << 20));           // 16 MB
  float*  locr  = (float*) (ws + (32u << 20));           //  8 MB
  ushort* WvT   = (ushort*)(ws + (40u << 20));           // 128 KB
  ushort* WoT   = (ushort*)(ws + (40u << 20) + (1u << 17));

  convert_val<<<NQ * CDIM / (256 * 4), 256, 0, stream>>>(value, val16);
  transpose_w<<<256, 256, 0, stream>>>(Wv, WvT);
  transpose_w<<<256, 256, 0, stream>>>(Wout, WoT);
  // vtab = bf16(value @ Wv + bv)
  gemm_mfma<<<(NQ / 128) * 2, 256, 0, stream>>>(val16, WvT, bv, vtab, nullptr, 1);
  // loc_raw = query @ [Wr_even | Wo_even]  (fp32)
  loc_gemm<<<NQ / 64, 256, 0, stream>>>(query, Wr, Wo, locr);
  // fused sampling/attention -> out2 (bf16)
  sample_attn<<<NQ / 4, 256, 0, stream>>>(query, key, vtab, locr, br, bo, out2);
  // out = out2 @ Wout + bout  (f32)
  gemm_mfma<<<(NQ / 128) * 2, 256, 0, stream>>>(out2, WoT, bout, nullptr, out, 0);
}

// Round 2
// 130.307 us; speedup vs baseline: 1.3516x; 1.3516x over previous
//
#include <hip/hip_runtime.h>
#include <hip/hip_bf16.h>
#include <stdint.h>

// Problem constants (fixed by the reference)
#define NQ    32768
#define NKV   32768
#define CDIM  256
#define NHEADS 8
#define NPTS  4
// Ch = 32, pairs (h,p) = 32, loc cols used = even cols only (x coord)

using bf16x8 = __attribute__((ext_vector_type(8))) short;
using f32x4  = __attribute__((ext_vector_type(4))) float;

static __device__ __forceinline__ ushort f2bf(float f) {
  uint32_t u = __float_as_uint(f);
  return (ushort)((u + 0x7FFFu + ((u >> 16) & 1u)) >> 16);  // RNE
}
static __device__ __forceinline__ float bf2f(ushort h) {
  return __uint_as_float(((uint32_t)h) << 16);
}
static __device__ __forceinline__ void async16(const void* g, void* l) {
  __builtin_amdgcn_global_load_lds(
      (const __attribute__((address_space(1))) uint32_t*)g,
      (__attribute__((address_space(3))) uint32_t*)l, 16, 0, 0);
}

// ---------------------------------------------------------------------------
// K0a: value f32 -> bf16 (row-major, same layout). 4 floats/thread.
__global__ __launch_bounds__(256) void convert_val(const float* __restrict__ V,
                                                   ushort* __restrict__ O) {
  int i = blockIdx.x * 256 + threadIdx.x;
  float4 v = *(const float4*)&V[(size_t)i * 4];
  ushort4 o;
  o.x = f2bf(v.x); o.y = f2bf(v.y); o.z = f2bf(v.z); o.w = f2bf(v.w);
  *(ushort4*)&O[(size_t)i * 4] = o;
}

// K0b: W [256][256] f32 -> W^T [256][256] bf16 (row j holds column j of W,
// k-contiguous — the layout the MFMA B-operand wants).
__global__ __launch_bounds__(256) void transpose_w(const float* __restrict__ W,
                                                   ushort* __restrict__ WT) {
  int j = blockIdx.x, k = threadIdx.x;
  WT[j * 256 + k] = f2bf(W[k * 256 + j]);
}

// ---------------------------------------------------------------------------
// K1/K3: bf16 MFMA GEMM  C[M,256] = A[M,256] * B + bias
//  A row-major bf16, BT = B^T row-major bf16. 128x128 tile, BK=32,
//  256 threads = 4 waves in 2x2, each wave 4x4 frags of 16x16x32.
__global__ __launch_bounds__(256) void gemm_mfma(
    const ushort* __restrict__ A, const ushort* __restrict__ BT,
    const float* __restrict__ bias, ushort* __restrict__ Cb,
    float* __restrict__ Cf, int out_bf16) {
  __shared__ ushort Alds[128 * 32];
  __shared__ ushort Blds[128 * 32];
  const int t = threadIdx.x;
  const int wave = t >> 6, lane = t & 63;
  const int mt = blockIdx.x >> 1, nt = blockIdx.x & 1;
  const int m0 = mt * 128, n0 = nt * 128;
  const int wr = wave >> 1, wc = wave & 1;
  const int r16 = lane & 15, kb = (lane >> 4) * 8;

  f32x4 acc[4][4] = {};

  for (int kt = 0; kt < 256; kt += 32) {
    __syncthreads();  // previous iter's frag reads done before overwrite
#pragma unroll
    for (int it = 0; it < 2; ++it) {
      int c = it * 256 + t;           // 16B chunk id: row = c>>2, sub = c&3
      int row = c >> 2, cc = c & 3;
      // dest base is wave-uniform; HW adds lane*16
      async16(A  + ((size_t)(m0 + row) * 256 + kt + cc * 8),
              Alds + (size_t)(it * 256 + wave * 64) * 8);
      async16(BT + ((size_t)(n0 + row) * 256 + kt + cc * 8),
              Blds + (size_t)(it * 256 + wave * 64) * 8);
    }
    __syncthreads();  // drains vmcnt -> staged data visible

    bf16x8 af[4], bfr[4];
#pragma unroll
    for (int m = 0; m < 4; ++m)
      af[m] = *(const bf16x8*)&Alds[(wr * 64 + m * 16 + r16) * 32 + kb];
#pragma unroll
    for (int n = 0; n < 4; ++n)
      bfr[n] = *(const bf16x8*)&Blds[(wc * 64 + n * 16 + r16) * 32 + kb];
#pragma unroll
    for (int m = 0; m < 4; ++m)
#pragma unroll
      for (int n = 0; n < 4; ++n)
        acc[m][n] = __builtin_amdgcn_mfma_f32_16x16x32_bf16(af[m], bfr[n],
                                                            acc[m][n], 0, 0, 0);
  }

  const int rg = lane >> 4;
#pragma unroll
  for (int m = 0; m < 4; ++m)
#pragma unroll
    for (int n = 0; n < 4; ++n) {
      int gc = n0 + wc * 64 + n * 16 + r16;
      float bb = bias[gc];
#pragma unroll
      for (int r = 0; r < 4; ++r) {
        int gr = m0 + wr * 64 + m * 16 + rg * 4 + r;
        float v = acc[m][n][r] + bb;
        if (out_bf16) Cb[(size_t)gr * 256 + gc] = f2bf(v);
        else          Cf[(size_t)gr * 256 + gc] = v;
      }
    }
}

// ---------------------------------------------------------------------------
// K2a: loc_raw[N,64] = query @ [Wr_even | Wo_even]   (fp32 — score path
// must be fp32-exact; bf16 here would flip sharp softmaxes at |x|~1e5).
// 64x64 tile, 256 threads, 4x4 regs/thread, BK=64, A staged transposed.
__global__ __launch_bounds__(256) void loc_gemm(const float* __restrict__ Q,
                                                const float* __restrict__ Wr,
                                                const float* __restrict__ Wo,
                                                float* __restrict__ locr) {
  __shared__ float AT[64][68];  // [k][m], pad 68 keeps 16B align + banks spread
  __shared__ float Bl[64][64];  // [k][j]
  const int m0 = blockIdx.x * 64;
  const int t = threadIdx.x;
  const int tr = t >> 4, tc = t & 15;
  float acc[4][4] = {};

  for (int k0 = 0; k0 < 256; k0 += 64) {
    __syncthreads();
#pragma unroll
    for (int i = 0; i < 4; ++i) {  // A: 64 rows x 64 k, stored transposed
      int row = (t >> 4) + 16 * i;
      int kk = (t & 15) * 4;
      float4 v = *(const float4*)&Q[(size_t)(m0 + row) * 256 + k0 + kk];
      AT[kk + 0][row] = v.x; AT[kk + 1][row] = v.y;
      AT[kk + 2][row] = v.z; AT[kk + 3][row] = v.w;
    }
#pragma unroll
    for (int i = 0; i < 16; ++i) { // B: even cols of Wr (j<32) / Wo (j>=32)
      int j = t & 63;
      int kk = (t >> 6) + 4 * i;
      float v = (j < 32) ? Wr[(size_t)(k0 + kk) * 64 + 2 * j]
                         : Wo[(size_t)(k0 + kk) * 64 + 2 * (j - 32)];
      Bl[kk][j] = v;
    }
    __syncthreads();
#pragma unroll 8
    for (int kk = 0; kk < 64; ++kk) {
      float4 a = *(const float4*)&AT[kk][tr * 4];
      float4 b = *(const float4*)&Bl[kk][tc * 4];
      float av[4] = {a.x, a.y, a.z, a.w};
      float bv4[4] = {b.x, b.y, b.z, b.w};
#pragma unroll
      for (int i = 0; i < 4; ++i)
#pragma unroll
        for (int jj = 0; jj < 4; ++jj) acc[i][jj] += av[i] * bv4[jj];
    }
  }
#pragma unroll
  for (int i = 0; i < 4; ++i)
#pragma unroll
    for (int jj = 0; jj < 4; ++jj)
      locr[(size_t)(m0 + tr * 4 + i) * 64 + tc * 4 + jj] = acc[i][jj];
}

// ---------------------------------------------------------------------------
// K2b: fused sampling + scores + softmax + weighted sum — transposed layout.
// One wave = 2 rows; lane = (half, j) with j = h*4+p. Each lane owns one
// sampling point: x0/x1/wx lane-local, 32-channel dot lane-local (serial
// fma), lerp lane-local. Only softmax-over-p (4 shuffles) and the output
// p-reduce (64 shuffles) cross lanes. ~34 shuffles/row vs 320 before.
__global__ __launch_bounds__(256) void sample_attn(
    const float* __restrict__ query, const float* __restrict__ key,
    const ushort* __restrict__ vtab, const float* __restrict__ locr,
    const float* __restrict__ br, const float* __restrict__ bo,
    ushort* __restrict__ out2) {
  const int wave = threadIdx.x >> 6, lane = threadIdx.x & 63;
  const int half = lane >> 5;          // which of the wave's 2 rows
  const int j = lane & 31;             // h*4+p
  const int h = j >> 2, p = j & 3;
  const int n = blockIdx.x * 8 + wave * 2 + half;
  const int Mm1 = NKV - 1;

  // sampling location for this lane's (n,h,p)
  float rr = locr[(size_t)n * 64 + j];
  float oo = locr[(size_t)n * 64 + 32 + j];
  float ref = 1.0f / (1.0f + expf(-(rr + br[2 * j])));
  float x = (ref + (oo + bo[2 * j])) * (float)Mm1;
  float xf = floorf(x);
  int x0 = (int)fminf(fmaxf(xf, 0.0f), (float)Mm1);
  int x1 = (x0 + 1 > Mm1) ? Mm1 : x0 + 1;
  float wx = x - (float)x0;
  float w0 = 1.0f - wx;

  const float*  kr0 = key  + (size_t)x0 * 256 + h * 32;
  const float*  kr1 = key  + (size_t)x1 * 256 + h * 32;
  const ushort* vr0 = vtab + (size_t)x0 * 256 + h * 32;
  const ushort* vr1 = vtab + (size_t)x1 * 256 + h * 32;
  const float*  qr  = query + (size_t)n * 256 + h * 32;

  float score = 0.0f;
  float sv[32];
#pragma unroll
  for (int cc = 0; cc < 32; cc += 4) {
    float4 k0v = *(const float4*)(kr0 + cc);
    float4 k1v = *(const float4*)(kr1 + cc);
    ushort4 v0v = *(const ushort4*)(vr0 + cc);
    ushort4 v1v = *(const ushort4*)(vr1 + cc);
    float4 qv  = *(const float4*)(qr + cc);
    float sk0 = w0 * k0v.x + wx * k1v.x;
    float sk1 = w0 * k0v.y + wx * k1v.y;
    float sk2 = w0 * k0v.z + wx * k1v.z;
    float sk3 = w0 * k0v.w + wx * k1v.w;
    score += qv.x * sk0 + qv.y * sk1 + qv.z * sk2 + qv.w * sk3;
    sv[cc + 0] = w0 * bf2f(v0v.x) + wx * bf2f(v1v.x);
    sv[cc + 1] = w0 * bf2f(v0v.y) + wx * bf2f(v1v.y);
    sv[cc + 2] = w0 * bf2f(v0v.z) + wx * bf2f(v1v.z);
    sv[cc + 3] = w0 * bf2f(v0v.w) + wx * bf2f(v1v.w);
  }
  score *= 0.17677669529663687f;  // 1/sqrt(32)

  // softmax over the 4 points (lanes j^1, j^2 are the same head, same half)
  float m1 = fmaxf(score, __shfl_xor(score, 1, 64));
  float mx = fmaxf(m1, __shfl_xor(m1, 2, 64));
  float e = expf(score - mx);
  float s1 = e + __shfl_xor(e, 1, 64);
  float ssum = s1 + __shfl_xor(s1, 2, 64);
  float attn = e / ssum;

  // output: o[c] = sum_p attn_p * sv_p[c]; reduce across the 4 p-lanes
  ushort ob[32];
#pragma unroll
  for (int c = 0; c < 32; ++c) {
    float t = attn * sv[c];
    t += __shfl_xor(t, 1, 64);
    t += __shfl_xor(t, 2, 64);
    ob[c] = f2bf(t);
  }
  if (p == 0) {
    ushort* dst = out2 + (size_t)n * 256 + h * 32;
#pragma unroll
    for (int c = 0; c < 32; c += 8) {
      ushort4 a = {ob[c], ob[c + 1], ob[c + 2], ob[c + 3]};
      ushort4 b = {ob[c + 4], ob[c + 5], ob[c + 6], ob[c + 7]};
      *(ushort4*)(dst + c) = a;
      *(ushort4*)(dst + c + 4) = b;
    }
  }
}

// ---------------------------------------------------------------------------
extern "C" void kernel_launch(void* const* d_in, const int* in_sizes, int n_in,
                              void* d_out, int out_size, void* d_ws, size_t ws_size,
                              hipStream_t stream) {
  const float* query = (const float*)d_in[0];
  const float* key   = (const float*)d_in[1];
  const float* value = (const float*)d_in[2];
  const float* Wr    = (const float*)d_in[3];
  const float* br    = (const float*)d_in[4];
  const float* Wo    = (const float*)d_in[5];
  const float* bo    = (const float*)d_in[6];
  const float* Wv    = (const float*)d_in[7];
  const float* bv    = (const float*)d_in[8];
  const float* Wout  = (const float*)d_in[9];
  const float* bout  = (const float*)d_in[10];
  float* out = (float*)d_out;

  char* ws = (char*)d_ws;
  // val16 (16MB) is dead after the Wv GEMM; out2 reuses its space.
  ushort* val16 = (ushort*)(ws);                         // 16 MB
  ushort* out2  = (ushort*)(ws);                         // 16 MB (alias, later)
  ushort* vtab  = (ushort*)(ws + (16u << 20));           // 16 MB
  float*  locr  = (float*) (ws + (32u << 20));           //  8 MB
  ushort* WvT   = (ushort*)(ws + (40u << 20));           // 128 KB
  ushort* WoT   = (ushort*)(ws + (40u << 20) + (1u << 17));

  convert_val<<<NQ * CDIM / (256 * 4), 256, 0, stream>>>(value, val16);
  transpose_w<<<256, 256, 0, stream>>>(Wv, WvT);
  transpose_w<<<256, 256, 0, stream>>>(Wout, WoT);
  // vtab = bf16(value @ Wv + bv)
  gemm_mfma<<<(NQ / 128) * 2, 256, 0, stream>>>(val16, WvT, bv, vtab, nullptr, 1);
  // loc_raw = query @ [Wr_even | Wo_even]  (fp32)
  loc_gemm<<<NQ / 64, 256, 0, stream>>>(query, Wr, Wo, locr);
  // fused sampling/attention -> out2 (bf16)
  sample_attn<<<NQ / 8, 256, 0, stream>>>(query, key, vtab, locr, br, bo, out2);
  // out = out2 @ Wout + bout  (f32)
  gemm_mfma<<<(NQ / 128) * 2, 256, 0, stream>>>(out2, WoT, bout, nullptr, out, 0);
}

// Round 3
// 125.152 us; speedup vs baseline: 1.4073x; 1.0412x over previous
//
#include <hip/hip_runtime.h>
#include <hip/hip_bf16.h>
#include <stdint.h>

// Problem constants (fixed by the reference)
#define NQ    32768
#define NKV   32768
#define CDIM  256
#define NHEADS 8
#define NPTS  4
// Ch = 32, pairs (h,p) = 32, loc cols used = even cols only (x coord)

using bf16x8 = __attribute__((ext_vector_type(8))) short;
using f32x4  = __attribute__((ext_vector_type(4))) float;
using u16x8  = __attribute__((ext_vector_type(8))) ushort;

static __device__ __forceinline__ ushort f2bf(float f) {
  uint32_t u = __float_as_uint(f);
  return (ushort)((u + 0x7FFFu + ((u >> 16) & 1u)) >> 16);  // RNE
}
static __device__ __forceinline__ float bf2f(ushort h) {
  return __uint_as_float(((uint32_t)h) << 16);
}
static __device__ __forceinline__ void async16(const void* g, void* l) {
  __builtin_amdgcn_global_load_lds(
      (const __attribute__((address_space(1))) uint32_t*)g,
      (__attribute__((address_space(3))) uint32_t*)l, 16, 0, 0);
}

// ---------------------------------------------------------------------------
// K0a: value f32 -> bf16 (row-major, same layout). 4 floats/thread.
__global__ __launch_bounds__(256) void convert_val(const float* __restrict__ V,
                                                   ushort* __restrict__ O) {
  int i = blockIdx.x * 256 + threadIdx.x;
  float4 v = *(const float4*)&V[(size_t)i * 4];
  ushort4 o;
  o.x = f2bf(v.x); o.y = f2bf(v.y); o.z = f2bf(v.z); o.w = f2bf(v.w);
  *(ushort4*)&O[(size_t)i * 4] = o;
}

// K0b: W [256][256] f32 -> W^T [256][256] bf16 (row j holds column j of W,
// k-contiguous — the layout the MFMA B-operand wants).
__global__ __launch_bounds__(256) void transpose_w(const float* __restrict__ W,
                                                   ushort* __restrict__ WT) {
  int j = blockIdx.x, k = threadIdx.x;
  WT[j * 256 + k] = f2bf(W[k * 256 + j]);
}

// ---------------------------------------------------------------------------
// K1/K3: bf16 MFMA GEMM  C[M,256] = A[M,256] * B + bias
//  A row-major bf16, BT = B^T row-major bf16. 128x128 tile, BK=32,
//  256 threads = 4 waves in 2x2, each wave 4x4 frags of 16x16x32.
__global__ __launch_bounds__(256) void gemm_mfma(
    const ushort* __restrict__ A, const ushort* __restrict__ BT,
    const float* __restrict__ bias, ushort* __restrict__ Cb,
    float* __restrict__ Cf, int out_bf16) {
  __shared__ ushort Alds[128 * 32];
  __shared__ ushort Blds[128 * 32];
  const int t = threadIdx.x;
  const int wave = t >> 6, lane = t & 63;
  const int mt = blockIdx.x >> 1, nt = blockIdx.x & 1;
  const int m0 = mt * 128, n0 = nt * 128;
  const int wr = wave >> 1, wc = wave & 1;
  const int r16 = lane & 15, kb = (lane >> 4) * 8;

  f32x4 acc[4][4] = {};

  for (int kt = 0; kt < 256; kt += 32) {
    __syncthreads();  // previous iter's frag reads done before overwrite
#pragma unroll
    for (int it = 0; it < 2; ++it) {
      int c = it * 256 + t;           // 16B chunk id: row = c>>2, sub = c&3
      int row = c >> 2, cc = c & 3;
      // dest base is wave-uniform; HW adds lane*16
      async16(A  + ((size_t)(m0 + row) * 256 + kt + cc * 8),
              Alds + (size_t)(it * 256 + wave * 64) * 8);
      async16(BT + ((size_t)(n0 + row) * 256 + kt + cc * 8),
              Blds + (size_t)(it * 256 + wave * 64) * 8);
    }
    __syncthreads();  // drains vmcnt -> staged data visible

    bf16x8 af[4], bfr[4];
#pragma unroll
    for (int m = 0; m < 4; ++m)
      af[m] = *(const bf16x8*)&Alds[(wr * 64 + m * 16 + r16) * 32 + kb];
#pragma unroll
    for (int n = 0; n < 4; ++n)
      bfr[n] = *(const bf16x8*)&Blds[(wc * 64 + n * 16 + r16) * 32 + kb];
#pragma unroll
    for (int m = 0; m < 4; ++m)
#pragma unroll
      for (int n = 0; n < 4; ++n)
        acc[m][n] = __builtin_amdgcn_mfma_f32_16x16x32_bf16(af[m], bfr[n],
                                                            acc[m][n], 0, 0, 0);
  }

  const int rg = lane >> 4;
#pragma unroll
  for (int m = 0; m < 4; ++m)
#pragma unroll
    for (int n = 0; n < 4; ++n) {
      int gc = n0 + wc * 64 + n * 16 + r16;
      float bb = bias[gc];
#pragma unroll
      for (int r = 0; r < 4; ++r) {
        int gr = m0 + wr * 64 + m * 16 + rg * 4 + r;
        float v = acc[m][n][r] + bb;
        if (out_bf16) Cb[(size_t)gr * 256 + gc] = f2bf(v);
        else          Cf[(size_t)gr * 256 + gc] = v;
      }
    }
}

// ---------------------------------------------------------------------------
// K2a: loc_raw[N,64] = query @ [Wr_even | Wo_even]   (fp32 — score path
// must be fp32-exact; bf16 here would flip sharp softmaxes at |x|~1e5).
// 64x64 tile, 256 threads, 4x4 regs/thread, BK=64, A staged transposed.
__global__ __launch_bounds__(256) void loc_gemm(const float* __restrict__ Q,
                                                const float* __restrict__ Wr,
                                                const float* __restrict__ Wo,
                                                float* __restrict__ locr) {
  __shared__ float AT[64][68];  // [k][m], pad 68 keeps 16B align + banks spread
  __shared__ float Bl[64][64];  // [k][j]
  const int m0 = blockIdx.x * 64;
  const int t = threadIdx.x;
  const int tr = t >> 4, tc = t & 15;
  float acc[4][4] = {};

  for (int k0 = 0; k0 < 256; k0 += 64) {
    __syncthreads();
#pragma unroll
    for (int i = 0; i < 4; ++i) {  // A: 64 rows x 64 k, stored transposed
      int row = (t >> 4) + 16 * i;
      int kk = (t & 15) * 4;
      float4 v = *(const float4*)&Q[(size_t)(m0 + row) * 256 + k0 + kk];
      AT[kk + 0][row] = v.x; AT[kk + 1][row] = v.y;
      AT[kk + 2][row] = v.z; AT[kk + 3][row] = v.w;
    }
#pragma unroll
    for (int i = 0; i < 16; ++i) { // B: even cols of Wr (j<32) / Wo (j>=32)
      int j = t & 63;
      int kk = (t >> 6) + 4 * i;
      float v = (j < 32) ? Wr[(size_t)(k0 + kk) * 64 + 2 * j]
                         : Wo[(size_t)(k0 + kk) * 64 + 2 * (j - 32)];
      Bl[kk][j] = v;
    }
    __syncthreads();
#pragma unroll 8
    for (int kk = 0; kk < 64; ++kk) {
      float4 a = *(const float4*)&AT[kk][tr * 4];
      float4 b = *(const float4*)&Bl[kk][tc * 4];
      float av[4] = {a.x, a.y, a.z, a.w};
      float bv4[4] = {b.x, b.y, b.z, b.w};
#pragma unroll
      for (int i = 0; i < 4; ++i)
#pragma unroll
        for (int jj = 0; jj < 4; ++jj) acc[i][jj] += av[i] * bv4[jj];
    }
  }
#pragma unroll
  for (int i = 0; i < 4; ++i)
#pragma unroll
    for (int jj = 0; jj < 4; ++jj)
      locr[(size_t)(m0 + tr * 4 + i) * 64 + tc * 4 + jj] = acc[i][jj];
}

// ---------------------------------------------------------------------------
// K2b: fused sampling + scores + softmax + weighted sum — transposed layout,
// max-MLP version. One wave = 2 rows; lane = (half, j=h*4+p). All ~32
// per-lane gather loads are issued up front into registers (112 data VGPRs)
// so they are ALL outstanding simultaneously; compute happens afterward.
// __launch_bounds__(256,2) lifts the VGPR cap so regalloc doesn't serialize
// the loads (round-2's VGPR=44 allowed only ~3 loads in flight).
__global__ __launch_bounds__(256, 2) void sample_attn(
    const float* __restrict__ query, const float* __restrict__ key,
    const ushort* __restrict__ vtab, const float* __restrict__ locr,
    const float* __restrict__ br, const float* __restrict__ bo,
    ushort* __restrict__ out2) {
  const int wave = threadIdx.x >> 6, lane = threadIdx.x & 63;
  const int half = lane >> 5;          // which of the wave's 2 rows
  const int j = lane & 31;             // h*4+p
  const int h = j >> 2, p = j & 3;
  const int n = blockIdx.x * 8 + wave * 2 + half;
  const int Mm1 = NKV - 1;

  // sampling location for this lane's (n,h,p)
  float rr = locr[(size_t)n * 64 + j];
  float oo = locr[(size_t)n * 64 + 32 + j];
  float ref = 1.0f / (1.0f + expf(-(rr + br[2 * j])));
  float x = (ref + (oo + bo[2 * j])) * (float)Mm1;
  float xf = floorf(x);
  int x0 = (int)fminf(fmaxf(xf, 0.0f), (float)Mm1);
  int x1 = (x0 + 1 > Mm1) ? Mm1 : x0 + 1;
  float wx = x - (float)x0;
  float w0 = 1.0f - wx;

  const float*  kr0 = key  + (size_t)x0 * 256 + h * 32;
  const float*  kr1 = key  + (size_t)x1 * 256 + h * 32;
  const ushort* vr0 = vtab + (size_t)x0 * 256 + h * 32;
  const ushort* vr1 = vtab + (size_t)x1 * 256 + h * 32;
  const float*  qr  = query + (size_t)n * 256 + h * 32;

  // ---- issue ALL loads before any consumption (32 per lane, independent)
  f32x4 k0r[8], k1r[8], qv8[8];
  u16x8 v0r[4], v1r[4];
#pragma unroll
  for (int i = 0; i < 8; ++i) k0r[i] = *(const f32x4*)(kr0 + i * 4);
#pragma unroll
  for (int i = 0; i < 8; ++i) k1r[i] = *(const f32x4*)(kr1 + i * 4);
#pragma unroll
  for (int i = 0; i < 4; ++i) v0r[i] = *(const u16x8*)(vr0 + i * 8);
#pragma unroll
  for (int i = 0; i < 4; ++i) v1r[i] = *(const u16x8*)(vr1 + i * 8);
#pragma unroll
  for (int i = 0; i < 8; ++i) qv8[i] = *(const f32x4*)(qr + i * 4);

  // ---- score (consumes k0r/k1r/qv8; v-loads keep draining meanwhile)
  float score = 0.0f;
#pragma unroll
  for (int i = 0; i < 8; ++i)
#pragma unroll
    for (int e = 0; e < 4; ++e)
      score += qv8[i][e] * (w0 * k0r[i][e] + wx * k1r[i][e]);
  score *= 0.17677669529663687f;  // 1/sqrt(32)

  // softmax over the 4 points (lanes j^1, j^2 are the same head, same half)
  float m1 = fmaxf(score, __shfl_xor(score, 1, 64));
  float mx = fmaxf(m1, __shfl_xor(m1, 2, 64));
  float e = expf(score - mx);
  float s1 = e + __shfl_xor(e, 1, 64);
  float ssum = s1 + __shfl_xor(s1, 2, 64);
  float attn = e / ssum;

  // ---- sampled values (consumes v0r/v1r)
  float sv[32];
#pragma unroll
  for (int i = 0; i < 4; ++i)
#pragma unroll
    for (int ee = 0; ee < 8; ++ee)
      sv[i * 8 + ee] = w0 * bf2f((ushort)v0r[i][ee]) +
                       wx * bf2f((ushort)v1r[i][ee]);

  // output: o[c] = sum_p attn_p * sv_p[c]; reduce across the 4 p-lanes
  ushort ob[32];
#pragma unroll
  for (int c = 0; c < 32; ++c) {
    float t = attn * sv[c];
    t += __shfl_xor(t, 1, 64);
    t += __shfl_xor(t, 2, 64);
    ob[c] = f2bf(t);
  }
  if (p == 0) {
    ushort* dst = out2 + (size_t)n * 256 + h * 32;
#pragma unroll
    for (int c = 0; c < 32; c += 8) {
      u16x8 w;
#pragma unroll
      for (int ee = 0; ee < 8; ++ee) w[ee] = ob[c + ee];
      *(u16x8*)(dst + c) = w;
    }
  }
}

// ---------------------------------------------------------------------------
extern "C" void kernel_launch(void* const* d_in, const int* in_sizes, int n_in,
                              void* d_out, int out_size, void* d_ws, size_t ws_size,
                              hipStream_t stream) {
  const float* query = (const float*)d_in[0];
  const float* key   = (const float*)d_in[1];
  const float* value = (const float*)d_in[2];
  const float* Wr    = (const float*)d_in[3];
  const float* br    = (const float*)d_in[4];
  const float* Wo    = (const float*)d_in[5];
  const float* bo    = (const float*)d_in[6];
  const float* Wv    = (const float*)d_in[7];
  const float* bv    = (const float*)d_in[8];
  const float* Wout  = (const float*)d_in[9];
  const float* bout  = (const float*)d_in[10];
  float* out = (float*)d_out;

  char* ws = (char*)d_ws;
  // val16 (16MB) is dead after the Wv GEMM; out2 reuses its space.
  ushort* val16 = (ushort*)(ws);                         // 16 MB
  ushort* out2  = (ushort*)(ws);                         // 16 MB (alias, later)
  ushort* vtab  = (ushort*)(ws + (16u << 20));           // 16 MB
  float*  locr  = (float*) (ws + (32u << 20));           //  8 MB
  ushort* WvT   = (ushort*)(ws + (40u << 20));           // 128 KB
  ushort* WoT   = (ushort*)(ws + (40u << 20) + (1u << 17));

  convert_val<<<NQ * CDIM / (256 * 4), 256, 0, stream>>>(value, val16);
  transpose_w<<<256, 256, 0, stream>>>(Wv, WvT);
  transpose_w<<<256, 256, 0, stream>>>(Wout, WoT);
  // vtab = bf16(value @ Wv + bv)
  gemm_mfma<<<(NQ / 128) * 2, 256, 0, stream>>>(val16, WvT, bv, vtab, nullptr, 1);
  // loc_raw = query @ [Wr_even | Wo_even]  (fp32)
  loc_gemm<<<NQ / 64, 256, 0, stream>>>(query, Wr, Wo, locr);
  // fused sampling/attention -> out2 (bf16)
  sample_attn<<<NQ / 8, 256, 0, stream>>>(query, key, vtab, locr, br, bo, out2);
  // out = out2 @ Wout + bout  (f32)
  gemm_mfma<<<(NQ / 128) * 2, 256, 0, stream>>>(out2, WoT, bout, nullptr, out, 0);
}

// Round 4
// 123.251 us; speedup vs baseline: 1.4290x; 1.0154x over previous
//
#include <hip/hip_runtime.h>
#include <hip/hip_bf16.h>
#include <stdint.h>

// Problem constants (fixed by the reference)
#define NQ    32768
#define NKV   32768
#define CDIM  256
#define NHEADS 8
#define NPTS  4
// Ch = 32, pairs (h,p) = 32, loc cols used = even cols only (x coord)

using bf16x8 = __attribute__((ext_vector_type(8))) short;
using f32x4  = __attribute__((ext_vector_type(4))) float;
using u16x8  = __attribute__((ext_vector_type(8))) ushort;

static __device__ __forceinline__ ushort f2bf(float f) {
  uint32_t u = __float_as_uint(f);
  return (ushort)((u + 0x7FFFu + ((u >> 16) & 1u)) >> 16);  // RNE
}
static __device__ __forceinline__ float bf2f(ushort h) {
  return __uint_as_float(((uint32_t)h) << 16);
}
static __device__ __forceinline__ void async16(const void* g, void* l) {
  __builtin_amdgcn_global_load_lds(
      (const __attribute__((address_space(1))) uint32_t*)g,
      (__attribute__((address_space(3))) uint32_t*)l, 16, 0, 0);
}
#define WAIT_VM0  do { asm volatile("s_waitcnt vmcnt(0)" ::: "memory"); \
                       __builtin_amdgcn_sched_barrier(0); } while (0)
#define WAIT_LGKM0 do { asm volatile("s_waitcnt lgkmcnt(0)" ::: "memory"); \
                        __builtin_amdgcn_sched_barrier(0); } while (0)

// ---------------------------------------------------------------------------
// K0a: value f32 -> bf16 (row-major, same layout). 4 floats/thread.
__global__ __launch_bounds__(256) void convert_val(const float* __restrict__ V,
                                                   ushort* __restrict__ O) {
  int i = blockIdx.x * 256 + threadIdx.x;
  float4 v = *(const float4*)&V[(size_t)i * 4];
  ushort4 o;
  o.x = f2bf(v.x); o.y = f2bf(v.y); o.z = f2bf(v.z); o.w = f2bf(v.w);
  *(ushort4*)&O[(size_t)i * 4] = o;
}

// K0b: W [256][256] f32 -> W^T [256][256] bf16 (row j holds column j of W,
// k-contiguous — the layout the MFMA B-operand wants).
__global__ __launch_bounds__(256) void transpose_w(const float* __restrict__ W,
                                                   ushort* __restrict__ WT) {
  int j = blockIdx.x, k = threadIdx.x;
  WT[j * 256 + k] = f2bf(W[k * 256 + j]);
}

// ---------------------------------------------------------------------------
// K1/K3: bf16 MFMA GEMM  C[M,256] = A[M,256] * B + bias
//  A row-major bf16, BT = B^T row-major bf16. 128x128 tile, BK=32,
//  256 threads = 4 waves in 2x2, each wave 4x4 frags of 16x16x32.
__global__ __launch_bounds__(256) void gemm_mfma(
    const ushort* __restrict__ A, const ushort* __restrict__ BT,
    const float* __restrict__ bias, ushort* __restrict__ Cb,
    float* __restrict__ Cf, int out_bf16) {
  __shared__ ushort Alds[128 * 32];
  __shared__ ushort Blds[128 * 32];
  const int t = threadIdx.x;
  const int wave = t >> 6, lane = t & 63;
  const int mt = blockIdx.x >> 1, nt = blockIdx.x & 1;
  const int m0 = mt * 128, n0 = nt * 128;
  const int wr = wave >> 1, wc = wave & 1;
  const int r16 = lane & 15, kb = (lane >> 4) * 8;

  f32x4 acc[4][4] = {};

  for (int kt = 0; kt < 256; kt += 32) {
    __syncthreads();  // previous iter's frag reads done before overwrite
#pragma unroll
    for (int it = 0; it < 2; ++it) {
      int c = it * 256 + t;           // 16B chunk id: row = c>>2, sub = c&3
      int row = c >> 2, cc = c & 3;
      // dest base is wave-uniform; HW adds lane*16
      async16(A  + ((size_t)(m0 + row) * 256 + kt + cc * 8),
              Alds + (size_t)(it * 256 + wave * 64) * 8);
      async16(BT + ((size_t)(n0 + row) * 256 + kt + cc * 8),
              Blds + (size_t)(it * 256 + wave * 64) * 8);
    }
    __syncthreads();  // drains vmcnt -> staged data visible

    bf16x8 af[4], bfr[4];
#pragma unroll
    for (int m = 0; m < 4; ++m)
      af[m] = *(const bf16x8*)&Alds[(wr * 64 + m * 16 + r16) * 32 + kb];
#pragma unroll
    for (int n = 0; n < 4; ++n)
      bfr[n] = *(const bf16x8*)&Blds[(wc * 64 + n * 16 + r16) * 32 + kb];
#pragma unroll
    for (int m = 0; m < 4; ++m)
#pragma unroll
      for (int n = 0; n < 4; ++n)
        acc[m][n] = __builtin_amdgcn_mfma_f32_16x16x32_bf16(af[m], bfr[n],
                                                            acc[m][n], 0, 0, 0);
  }

  const int rg = lane >> 4;
#pragma unroll
  for (int m = 0; m < 4; ++m)
#pragma unroll
    for (int n = 0; n < 4; ++n) {
      int gc = n0 + wc * 64 + n * 16 + r16;
      float bb = bias[gc];
#pragma unroll
      for (int r = 0; r < 4; ++r) {
        int gr = m0 + wr * 64 + m * 16 + rg * 4 + r;
        float v = acc[m][n][r] + bb;
        if (out_bf16) Cb[(size_t)gr * 256 + gc] = f2bf(v);
        else          Cf[(size_t)gr * 256 + gc] = v;
      }
    }
}

// ---------------------------------------------------------------------------
// K2a: loc_raw[N,64] = query @ [Wr_even | Wo_even]   (fp32 — score path
// must be fp32-exact; bf16 here would flip sharp softmaxes at |x|~1e5).
// 64x64 tile, 256 threads, 4x4 regs/thread, BK=64, A staged transposed.
__global__ __launch_bounds__(256) void loc_gemm(const float* __restrict__ Q,
                                                const float* __restrict__ Wr,
                                                const float* __restrict__ Wo,
                                                float* __restrict__ locr) {
  __shared__ float AT[64][68];  // [k][m], pad 68 keeps 16B align + banks spread
  __shared__ float Bl[64][64];  // [k][j]
  const int m0 = blockIdx.x * 64;
  const int t = threadIdx.x;
  const int tr = t >> 4, tc = t & 15;
  float acc[4][4] = {};

  for (int k0 = 0; k0 < 256; k0 += 64) {
    __syncthreads();
#pragma unroll
    for (int i = 0; i < 4; ++i) {  // A: 64 rows x 64 k, stored transposed
      int row = (t >> 4) + 16 * i;
      int kk = (t & 15) * 4;
      float4 v = *(const float4*)&Q[(size_t)(m0 + row) * 256 + k0 + kk];
      AT[kk + 0][row] = v.x; AT[kk + 1][row] = v.y;
      AT[kk + 2][row] = v.z; AT[kk + 3][row] = v.w;
    }
#pragma unroll
    for (int i = 0; i < 16; ++i) { // B: even cols of Wr (j<32) / Wo (j>=32)
      int j = t & 63;
      int kk = (t >> 6) + 4 * i;
      float v = (j < 32) ? Wr[(size_t)(k0 + kk) * 64 + 2 * j]
                         : Wo[(size_t)(k0 + kk) * 64 + 2 * (j - 32)];
      Bl[kk][j] = v;
    }
    __syncthreads();
#pragma unroll 8
    for (int kk = 0; kk < 64; ++kk) {
      float4 a = *(const float4*)&AT[kk][tr * 4];
      float4 b = *(const float4*)&Bl[kk][tc * 4];
      float av[4] = {a.x, a.y, a.z, a.w};
      float bv4[4] = {b.x, b.y, b.z, b.w};
#pragma unroll
      for (int i = 0; i < 4; ++i)
#pragma unroll
        for (int jj = 0; jj < 4; ++jj) acc[i][jj] += av[i] * bv4[jj];
    }
  }
#pragma unroll
  for (int i = 0; i < 4; ++i)
#pragma unroll
    for (int jj = 0; jj < 4; ++jj)
      locr[(size_t)(m0 + tr * 4 + i) * 64 + tc * 4 + jj] = acc[i][jj];
}

// ---------------------------------------------------------------------------
// K2b: fused sampling + attention, LDS-staged gathers.
// Wave = 2 rows (64 points); lane owns point pt = lane = half*32 + h*4 + p.
// Gathers go global->LDS via global_load_lds with per-lane global addresses:
// 8 lanes fetch the 8 16B-chunks of ONE point's 128B k-slice -> coalescer
// merges to 1 line (8 lines/instr vs 64 divergent before). Chunk index is
// XOR-swizzled (^pt&7) on the GLOBAL side (LDS dest must stay linear) so
// read-back ds_read_b128 spreads across all 8 bank-quads. One 8KB buffer
// per wave, reused k0 -> k1 -> v0+v1 with explicit vmcnt/lgkm fences
// (wave-private: no barriers).
__global__ __launch_bounds__(256, 4) void sample_attn(
    const float* __restrict__ query, const float* __restrict__ key,
    const ushort* __restrict__ vtab, const float* __restrict__ locr,
    const float* __restrict__ br, const float* __restrict__ bo,
    ushort* __restrict__ out2) {
  __shared__ char smem[4][8192];
  const int wave = threadIdx.x >> 6, lane = threadIdx.x & 63;
  const int half = lane >> 5;
  const int j = lane & 31;             // h*4+p
  const int h = j >> 2, p = j & 3;
  const int n = blockIdx.x * 8 + wave * 2 + half;
  const int Mm1 = NKV - 1;
  char* lb = smem[wave];

  // sampling location for this lane's point
  float rr = locr[(size_t)n * 64 + j];
  float oo = locr[(size_t)n * 64 + 32 + j];
  float ref = 1.0f / (1.0f + expf(-(rr + br[2 * j])));
  float x = (ref + (oo + bo[2 * j])) * (float)Mm1;
  float xf = floorf(x);
  int x0 = (int)fminf(fmaxf(xf, 0.0f), (float)Mm1);
  float wx = x - (float)x0;
  float w0 = 1.0f - wx;

  // staging role: this lane fetches chunk (s7 ^ pt&7) of point pt=i*8+ptg
  const int ptg = lane >> 3, s7 = lane & 7;
  const int kchunk = s7 ^ ptg;         // pt&7 == ptg for every i (i*8%8==0)
  int x0b[8], x1b[8];
#pragma unroll
  for (int i = 0; i < 8; ++i) {
    x0b[i] = __shfl(x0, i * 8 + ptg, 64);
    x1b[i] = (x0b[i] + 1 > Mm1) ? Mm1 : x0b[i] + 1;
  }

  // ---- phase 1: stage k0 slices (64 pts x 128B = 8KB), q direct
#pragma unroll
  for (int i = 0; i < 8; ++i) {
    int hp = ((i * 8 + ptg) & 31) >> 2;
    async16(key + (size_t)x0b[i] * 256 + hp * 32 + kchunk * 4, lb + i * 1024);
  }
  const float* qr = query + (size_t)n * 256 + h * 32;
  f32x4 qv[8];
#pragma unroll
  for (int i = 0; i < 8; ++i) qv[i] = *(const f32x4*)(qr + i * 4);

  WAIT_VM0;
  float dot0 = 0.f;
  {
    f32x4 kv[8];
#pragma unroll
    for (int c = 0; c < 8; ++c)
      kv[c] = *(const f32x4*)(lb + (lane * 8 + (c ^ (lane & 7))) * 16);
#pragma unroll
    for (int c = 0; c < 8; ++c)
#pragma unroll
      for (int e = 0; e < 4; ++e) dot0 += qv[c][e] * kv[c][e];
  }
  WAIT_LGKM0;  // k0 reads retired before buffer reuse

  // ---- phase 2: stage k1
#pragma unroll
  for (int i = 0; i < 8; ++i) {
    int hp = ((i * 8 + ptg) & 31) >> 2;
    async16(key + (size_t)x1b[i] * 256 + hp * 32 + kchunk * 4, lb + i * 1024);
  }
  WAIT_VM0;
  float dot1 = 0.f;
  {
    f32x4 kv[8];
#pragma unroll
    for (int c = 0; c < 8; ++c)
      kv[c] = *(const f32x4*)(lb + (lane * 8 + (c ^ (lane & 7))) * 16);
#pragma unroll
    for (int c = 0; c < 8; ++c)
#pragma unroll
      for (int e = 0; e < 4; ++e) dot1 += qv[c][e] * kv[c][e];
  }
  WAIT_LGKM0;  // k1 reads retired before buffer reuse

  // ---- phase 3: stage v0+v1 (64 pts x (64+64)B = 8KB); softmax overlaps
  // slot (pt, s7) holds (which,chunk) = s7 ^ (pt&7): which=eff>>2, cv=eff&3
#pragma unroll
  for (int i = 0; i < 8; ++i) {
    int hp = ((i * 8 + ptg) & 31) >> 2;
    int row = (kchunk & 4) ? x1b[i] : x0b[i];
    async16(vtab + (size_t)row * 256 + hp * 32 + (kchunk & 3) * 8,
            lb + i * 1024);
  }

  float score = (w0 * dot0 + wx * dot1) * 0.17677669529663687f;  // 1/sqrt(32)
  float m1 = fmaxf(score, __shfl_xor(score, 1, 64));
  float mx = fmaxf(m1, __shfl_xor(m1, 2, 64));
  float e0 = expf(score - mx);
  float s1 = e0 + __shfl_xor(e0, 1, 64);
  float ssum = s1 + __shfl_xor(s1, 2, 64);
  float attn = e0 / ssum;
  float c0 = attn * w0, c1 = attn * wx;
  // distribute the quad's coefficients; m-th value belongs to point p^m
  float c0a = c0,                      c1a = c1;
  float c0b = __shfl_xor(c0, 1, 64),   c1b = __shfl_xor(c1, 1, 64);
  float c0c = __shfl_xor(c0, 2, 64),   c1c = __shfl_xor(c1, 2, 64);
  float c0d = __shfl_xor(c0b, 2, 64),  c1d = __shfl_xor(c1b, 2, 64);

  WAIT_VM0;

  // each lane combines channels [p*8, p*8+8) over the head's 4 points
  float acc[8] = {};
  const int base = half * 32 + h * 4;
#pragma unroll
  for (int m = 0; m < 4; ++m) {
    int pt2 = base + (p ^ m);
    float cc0 = (m == 0) ? c0a : (m == 1) ? c0b : (m == 2) ? c0c : c0d;
    float cc1 = (m == 0) ? c1a : (m == 1) ? c1b : (m == 2) ? c1c : c1d;
    u16x8 v0 = *(const u16x8*)(lb + (pt2 * 8 + (p       ^ (pt2 & 7))) * 16);
    u16x8 v1 = *(const u16x8*)(lb + (pt2 * 8 + ((4 + p) ^ (pt2 & 7))) * 16);
#pragma unroll
    for (int e = 0; e < 8; ++e)
      acc[e] += cc0 * bf2f((ushort)v0[e]) + cc1 * bf2f((ushort)v1[e]);
  }
  u16x8 ow;
#pragma unroll
  for (int e = 0; e < 8; ++e) ow[e] = f2bf(acc[e]);
  *(u16x8*)(out2 + (size_t)n * 256 + h * 32 + p * 8) = ow;
}

// ---------------------------------------------------------------------------
extern "C" void kernel_launch(void* const* d_in, const int* in_sizes, int n_in,
                              void* d_out, int out_size, void* d_ws, size_t ws_size,
                              hipStream_t stream) {
  const float* query = (const float*)d_in[0];
  const float* key   = (const float*)d_in[1];
  const float* value = (const float*)d_in[2];
  const float* Wr    = (const float*)d_in[3];
  const float* br    = (const float*)d_in[4];
  const float* Wo    = (const float*)d_in[5];
  const float* bo    = (const float*)d_in[6];
  const float* Wv    = (const float*)d_in[7];
  const float* bv    = (const float*)d_in[8];
  const float* Wout  = (const float*)d_in[9];
  const float* bout  = (const float*)d_in[10];
  float* out = (float*)d_out;

  char* ws = (char*)d_ws;
  // val16 (16MB) is dead after the Wv GEMM; out2 reuses its space.
  ushort* val16 = (ushort*)(ws);                         // 16 MB
  ushort* out2  = (ushort*)(ws);                         // 16 MB (alias, later)
  ushort* vtab  = (ushort*)(ws + (16u << 20));           // 16 MB
  float*  locr  = (float*) (ws + (32u << 20));           //  8 MB
  ushort* WvT   = (ushort*)(ws + (40u << 20));           // 128 KB
  ushort* WoT   = (ushort*)(ws + (40u << 20) + (1u << 17));

  convert_val<<<NQ * CDIM / (256 * 4), 256, 0, stream>>>(value, val16);
  transpose_w<<<256, 256, 0, stream>>>(Wv, WvT);
  transpose_w<<<256, 256, 0, stream>>>(Wout, WoT);
  // vtab = bf16(value @ Wv + bv)
  gemm_mfma<<<(NQ / 128) * 2, 256, 0, stream>>>(val16, WvT, bv, vtab, nullptr, 1);
  // loc_raw = query @ [Wr_even | Wo_even]  (fp32)
  loc_gemm<<<NQ / 64, 256, 0, stream>>>(query, Wr, Wo, locr);
  // fused sampling/attention -> out2 (bf16)
  sample_attn<<<NQ / 8, 256, 0, stream>>>(query, key, vtab, locr, br, bo, out2);
  // out = out2 @ Wout + bout  (f32)
  gemm_mfma<<<(NQ / 128) * 2, 256, 0, stream>>>(out2, WoT, bout, nullptr, out, 0);
}

// Round 5
// 108.153 us; speedup vs baseline: 1.6285x; 1.1396x over previous
//
#include <hip/hip_runtime.h>
#include <hip/hip_bf16.h>
#include <stdint.h>

// Problem constants (fixed by the reference)
#define NQ    32768
#define NKV   32768
#define CDIM  256
#define NHEADS 8
#define NPTS  4
// Ch = 32, pairs (h,p) = 32, loc cols used = even cols only (x coord)

using bf16x8 = __attribute__((ext_vector_type(8))) short;
using f32x4  = __attribute__((ext_vector_type(4))) float;
using u16x8  = __attribute__((ext_vector_type(8))) ushort;

static __device__ __forceinline__ ushort f2bf(float f) {
  uint32_t u = __float_as_uint(f);
  return (ushort)((u + 0x7FFFu + ((u >> 16) & 1u)) >> 16);  // RNE
}
static __device__ __forceinline__ float bf2f(ushort h) {
  return __uint_as_float(((uint32_t)h) << 16);
}
static __device__ __forceinline__ void async16(const void* g, void* l) {
  __builtin_amdgcn_global_load_lds(
      (const __attribute__((address_space(1))) uint32_t*)g,
      (__attribute__((address_space(3))) uint32_t*)l, 16, 0, 0);
}

// K0b: W [256][256] f32 -> W^T [256][256] bf16 (row j holds column j of W,
// k-contiguous — the layout the MFMA B-operand wants).
__global__ __launch_bounds__(256) void transpose_w(const float* __restrict__ W,
                                                   ushort* __restrict__ WT) {
  int j = blockIdx.x, k = threadIdx.x;
  WT[j * 256 + k] = f2bf(W[k * 256 + j]);
}

// ---------------------------------------------------------------------------
// K3: bf16 MFMA GEMM  C[M,256] = A[M,256] * B + bias   (A already bf16)
//  A row-major bf16, BT = B^T row-major bf16. 128x128 tile, BK=32,
//  256 threads = 4 waves in 2x2, each wave 4x4 frags of 16x16x32.
__global__ __launch_bounds__(256) void gemm_mfma(
    const ushort* __restrict__ A, const ushort* __restrict__ BT,
    const float* __restrict__ bias, ushort* __restrict__ Cb,
    float* __restrict__ Cf, int out_bf16) {
  __shared__ ushort Alds[128 * 32];
  __shared__ ushort Blds[128 * 32];
  const int t = threadIdx.x;
  const int wave = t >> 6, lane = t & 63;
  const int mt = blockIdx.x >> 1, nt = blockIdx.x & 1;
  const int m0 = mt * 128, n0 = nt * 128;
  const int wr = wave >> 1, wc = wave & 1;
  const int r16 = lane & 15, kb = (lane >> 4) * 8;

  f32x4 acc[4][4] = {};

  for (int kt = 0; kt < 256; kt += 32) {
    __syncthreads();  // previous iter's frag reads done before overwrite
#pragma unroll
    for (int it = 0; it < 2; ++it) {
      int c = it * 256 + t;           // 16B chunk id: row = c>>2, sub = c&3
      int row = c >> 2, cc = c & 3;
      // dest base is wave-uniform; HW adds lane*16
      async16(A  + ((size_t)(m0 + row) * 256 + kt + cc * 8),
              Alds + (size_t)(it * 256 + wave * 64) * 8);
      async16(BT + ((size_t)(n0 + row) * 256 + kt + cc * 8),
              Blds + (size_t)(it * 256 + wave * 64) * 8);
    }
    __syncthreads();  // drains vmcnt -> staged data visible

    bf16x8 af[4], bfr[4];
#pragma unroll
    for (int m = 0; m < 4; ++m)
      af[m] = *(const bf16x8*)&Alds[(wr * 64 + m * 16 + r16) * 32 + kb];
#pragma unroll
    for (int n = 0; n < 4; ++n)
      bfr[n] = *(const bf16x8*)&Blds[(wc * 64 + n * 16 + r16) * 32 + kb];
#pragma unroll
    for (int m = 0; m < 4; ++m)
#pragma unroll
      for (int n = 0; n < 4; ++n)
        acc[m][n] = __builtin_amdgcn_mfma_f32_16x16x32_bf16(af[m], bfr[n],
                                                            acc[m][n], 0, 0, 0);
  }

  const int rg = lane >> 4;
#pragma unroll
  for (int m = 0; m < 4; ++m)
#pragma unroll
    for (int n = 0; n < 4; ++n) {
      int gc = n0 + wc * 64 + n * 16 + r16;
      float bb = bias[gc];
#pragma unroll
      for (int r = 0; r < 4; ++r) {
        int gr = m0 + wr * 64 + m * 16 + rg * 4 + r;
        float v = acc[m][n][r] + bb;
        if (out_bf16) Cb[(size_t)gr * 256 + gc] = f2bf(v);
        else          Cf[(size_t)gr * 256 + gc] = v;
      }
    }
}

// K1: same GEMM but A is f32 (value matrix) — converted to bf16 in-register
// during staging (fuses the old convert_val pass; saves 48MB HBM + a launch).
__global__ __launch_bounds__(256) void gemm_mfma_fa(
    const float* __restrict__ Af, const ushort* __restrict__ BT,
    const float* __restrict__ bias, ushort* __restrict__ Cb) {
  __shared__ ushort Alds[128 * 32];
  __shared__ ushort Blds[128 * 32];
  const int t = threadIdx.x;
  const int wave = t >> 6, lane = t & 63;
  const int mt = blockIdx.x >> 1, nt = blockIdx.x & 1;
  const int m0 = mt * 128, n0 = nt * 128;
  const int wr = wave >> 1, wc = wave & 1;
  const int r16 = lane & 15, kb = (lane >> 4) * 8;

  f32x4 acc[4][4] = {};

  for (int kt = 0; kt < 256; kt += 32) {
    __syncthreads();
#pragma unroll
    for (int it = 0; it < 2; ++it) {  // B via global_load_lds (bf16 already)
      int c = it * 256 + t;
      int row = c >> 2, cc = c & 3;
      async16(BT + ((size_t)(n0 + row) * 256 + kt + cc * 8),
              Blds + (size_t)(it * 256 + wave * 64) * 8);
    }
#pragma unroll
    for (int it = 0; it < 2; ++it) {  // A: f32 -> reg -> bf16 -> ds_write
      int c = it * 256 + t;
      int row = c >> 2, cc = c & 3;
      const float* src = Af + (size_t)(m0 + row) * 256 + kt + cc * 8;
      f32x4 a = *(const f32x4*)src;
      f32x4 b = *(const f32x4*)(src + 4);
      u16x8 w;
#pragma unroll
      for (int e = 0; e < 4; ++e) { w[e] = f2bf(a[e]); w[4 + e] = f2bf(b[e]); }
      *(u16x8*)&Alds[(size_t)c * 8] = w;   // c*8 == row*32 + cc*8
    }
    __syncthreads();  // covers vmcnt (B) + lgkm (A ds_write)

    bf16x8 af[4], bfr[4];
#pragma unroll
    for (int m = 0; m < 4; ++m)
      af[m] = *(const bf16x8*)&Alds[(wr * 64 + m * 16 + r16) * 32 + kb];
#pragma unroll
    for (int n = 0; n < 4; ++n)
      bfr[n] = *(const bf16x8*)&Blds[(wc * 64 + n * 16 + r16) * 32 + kb];
#pragma unroll
    for (int m = 0; m < 4; ++m)
#pragma unroll
      for (int n = 0; n < 4; ++n)
        acc[m][n] = __builtin_amdgcn_mfma_f32_16x16x32_bf16(af[m], bfr[n],
                                                            acc[m][n], 0, 0, 0);
  }

  const int rg = lane >> 4;
#pragma unroll
  for (int m = 0; m < 4; ++m)
#pragma unroll
    for (int n = 0; n < 4; ++n) {
      int gc = n0 + wc * 64 + n * 16 + r16;
      float bb = bias[gc];
#pragma unroll
      for (int r = 0; r < 4; ++r) {
        int gr = m0 + wr * 64 + m * 16 + rg * 4 + r;
        Cb[(size_t)gr * 256 + gc] = f2bf(acc[m][n][r] + bb);
      }
    }
}

// ---------------------------------------------------------------------------
// K2a: loc_raw[N,64] = query @ [Wr_even | Wo_even]   (fp32 — score path
// must be fp32-exact; bf16 here would flip sharp softmaxes at |x|~1e5).
// 64x64 tile, 256 threads, 4x4 regs/thread, BK=64, A staged transposed.
__global__ __launch_bounds__(256) void loc_gemm(const float* __restrict__ Q,
                                                const float* __restrict__ Wr,
                                                const float* __restrict__ Wo,
                                                float* __restrict__ locr) {
  __shared__ float AT[64][68];  // [k][m], pad 68 keeps 16B align + banks spread
  __shared__ float Bl[64][64];  // [k][j]
  const int m0 = blockIdx.x * 64;
  const int t = threadIdx.x;
  const int tr = t >> 4, tc = t & 15;
  float acc[4][4] = {};

  for (int k0 = 0; k0 < 256; k0 += 64) {
    __syncthreads();
#pragma unroll
    for (int i = 0; i < 4; ++i) {  // A: 64 rows x 64 k, stored transposed
      int row = (t >> 4) + 16 * i;
      int kk = (t & 15) * 4;
      float4 v = *(const float4*)&Q[(size_t)(m0 + row) * 256 + k0 + kk];
      AT[kk + 0][row] = v.x; AT[kk + 1][row] = v.y;
      AT[kk + 2][row] = v.z; AT[kk + 3][row] = v.w;
    }
#pragma unroll
    for (int i = 0; i < 16; ++i) { // B: even cols of Wr (j<32) / Wo (j>=32)
      int j = t & 63;
      int kk = (t >> 6) + 4 * i;
      float v = (j < 32) ? Wr[(size_t)(k0 + kk) * 64 + 2 * j]
                         : Wo[(size_t)(k0 + kk) * 64 + 2 * (j - 32)];
      Bl[kk][j] = v;
    }
    __syncthreads();
#pragma unroll 8
    for (int kk = 0; kk < 64; ++kk) {
      float4 a = *(const float4*)&AT[kk][tr * 4];
      float4 b = *(const float4*)&Bl[kk][tc * 4];
      float av[4] = {a.x, a.y, a.z, a.w};
      float bv4[4] = {b.x, b.y, b.z, b.w};
#pragma unroll
      for (int i = 0; i < 4; ++i)
#pragma unroll
        for (int jj = 0; jj < 4; ++jj) acc[i][jj] += av[i] * bv4[jj];
    }
  }
#pragma unroll
  for (int i = 0; i < 4; ++i)
#pragma unroll
    for (int jj = 0; jj < 4; ++jj)
      locr[(size_t)(m0 + tr * 4 + i) * 64 + tc * 4 + jj] = acc[i][jj];
}

// ---------------------------------------------------------------------------
// K2b: fused sampling + attention — forced-batch register gathers.
// Wave = 2 rows; lane = (half, j=h*4+p) owns one sampling point with its 32
// channels in-register. ALL 32 16B gather loads per lane are issued before a
// sched_barrier(0) fence, forcing ~128 data VGPRs live and 32 loads in
// flight per wave (vs ~3 in r3 when regalloc serialized, 8 in r4's LDS
// phases). Order k0,k1,q,v: score compute only needs vmcnt<=8, so the v
// loads keep draining underneath it.
__global__ __launch_bounds__(256, 2) void sample_attn(
    const float* __restrict__ query, const float* __restrict__ key,
    const ushort* __restrict__ vtab, const float* __restrict__ locr,
    const float* __restrict__ br, const float* __restrict__ bo,
    ushort* __restrict__ out2) {
  const int wave = threadIdx.x >> 6, lane = threadIdx.x & 63;
  const int half = lane >> 5;          // which of the wave's 2 rows
  const int j = lane & 31;             // h*4+p
  const int h = j >> 2, p = j & 3;
  const int n = blockIdx.x * 8 + wave * 2 + half;
  const int Mm1 = NKV - 1;

  // sampling location for this lane's (n,h,p)
  float rr = locr[(size_t)n * 64 + j];
  float oo = locr[(size_t)n * 64 + 32 + j];
  float ref = 1.0f / (1.0f + expf(-(rr + br[2 * j])));
  float x = (ref + (oo + bo[2 * j])) * (float)Mm1;
  float xf = floorf(x);
  int x0 = (int)fminf(fmaxf(xf, 0.0f), (float)Mm1);
  int x1 = (x0 + 1 > Mm1) ? Mm1 : x0 + 1;
  float wx = x - (float)x0;
  float w0 = 1.0f - wx;

  const float*  kr0 = key  + (size_t)x0 * 256 + h * 32;
  const float*  kr1 = key  + (size_t)x1 * 256 + h * 32;
  const ushort* vr0 = vtab + (size_t)x0 * 256 + h * 32;
  const ushort* vr1 = vtab + (size_t)x1 * 256 + h * 32;
  const float*  qr  = query + (size_t)n * 256 + h * 32;

  // ---- issue ALL loads; fence pins them before any consumer
  f32x4 k0r[8], k1r[8], qv8[8];
  u16x8 v0r[4], v1r[4];
#pragma unroll
  for (int i = 0; i < 8; ++i) k0r[i] = *(const f32x4*)(kr0 + i * 4);
#pragma unroll
  for (int i = 0; i < 8; ++i) k1r[i] = *(const f32x4*)(kr1 + i * 4);
#pragma unroll
  for (int i = 0; i < 8; ++i) qv8[i] = *(const f32x4*)(qr + i * 4);
#pragma unroll
  for (int i = 0; i < 4; ++i) v0r[i] = *(const u16x8*)(vr0 + i * 8);
#pragma unroll
  for (int i = 0; i < 4; ++i) v1r[i] = *(const u16x8*)(vr1 + i * 8);
  __builtin_amdgcn_sched_barrier(0);

  // ---- score: dot0/dot1 then lerp in score space (== lerp-then-dot)
  float dot0 = 0.f, dot1 = 0.f;
#pragma unroll
  for (int i = 0; i < 8; ++i)
#pragma unroll
    for (int e = 0; e < 4; ++e) {
      dot0 += qv8[i][e] * k0r[i][e];
      dot1 += qv8[i][e] * k1r[i][e];
    }
  float score = (w0 * dot0 + wx * dot1) * 0.17677669529663687f;  // 1/sqrt(32)

  // softmax over the 4 points (lanes j^1, j^2 are the same head, same half)
  float m1 = fmaxf(score, __shfl_xor(score, 1, 64));
  float mx = fmaxf(m1, __shfl_xor(m1, 2, 64));
  float e = expf(score - mx);
  float s1 = e + __shfl_xor(e, 1, 64);
  float ssum = s1 + __shfl_xor(s1, 2, 64);
  float attn = e / ssum;

  // ---- sampled values (consumes v0r/v1r)
  float sv[32];
#pragma unroll
  for (int i = 0; i < 4; ++i)
#pragma unroll
    for (int ee = 0; ee < 8; ++ee)
      sv[i * 8 + ee] = w0 * bf2f((ushort)v0r[i][ee]) +
                       wx * bf2f((ushort)v1r[i][ee]);

  // output: o[c] = sum_p attn_p * sv_p[c]; reduce across the 4 p-lanes
  ushort ob[32];
#pragma unroll
  for (int c = 0; c < 32; ++c) {
    float t = attn * sv[c];
    t += __shfl_xor(t, 1, 64);
    t += __shfl_xor(t, 2, 64);
    ob[c] = f2bf(t);
  }
  if (p == 0) {
    ushort* dst = out2 + (size_t)n * 256 + h * 32;
#pragma unroll
    for (int c = 0; c < 32; c += 8) {
      u16x8 w;
#pragma unroll
      for (int ee = 0; ee < 8; ++ee) w[ee] = ob[c + ee];
      *(u16x8*)(dst + c) = w;
    }
  }
}

// ---------------------------------------------------------------------------
extern "C" void kernel_launch(void* const* d_in, const int* in_sizes, int n_in,
                              void* d_out, int out_size, void* d_ws, size_t ws_size,
                              hipStream_t stream) {
  const float* query = (const float*)d_in[0];
  const float* key   = (const float*)d_in[1];
  const float* value = (const float*)d_in[2];
  const float* Wr    = (const float*)d_in[3];
  const float* br    = (const float*)d_in[4];
  const float* Wo    = (const float*)d_in[5];
  const float* bo    = (const float*)d_in[6];
  const float* Wv    = (const float*)d_in[7];
  const float* bv    = (const float*)d_in[8];
  const float* Wout  = (const float*)d_in[9];
  const float* bout  = (const float*)d_in[10];
  float* out = (float*)d_out;

  char* ws = (char*)d_ws;
  ushort* out2  = (ushort*)(ws);                         // 16 MB
  ushort* vtab  = (ushort*)(ws + (16u << 20));           // 16 MB
  float*  locr  = (float*) (ws + (32u << 20));           //  8 MB
  ushort* WvT   = (ushort*)(ws + (40u << 20));           // 128 KB
  ushort* WoT   = (ushort*)(ws + (40u << 20) + (1u << 17));

  transpose_w<<<256, 256, 0, stream>>>(Wv, WvT);
  transpose_w<<<256, 256, 0, stream>>>(Wout, WoT);
  // vtab = bf16(value @ Wv + bv)  (A converted f32->bf16 during staging)
  gemm_mfma_fa<<<(NQ / 128) * 2, 256, 0, stream>>>(value, WvT, bv, vtab);
  // loc_raw = query @ [Wr_even | Wo_even]  (fp32)
  loc_gemm<<<NQ / 64, 256, 0, stream>>>(query, Wr, Wo, locr);
  // fused sampling/attention -> out2 (bf16)
  sample_attn<<<NQ / 8, 256, 0, stream>>>(query, key, vtab, locr, br, bo, out2);
  // out = out2 @ Wout + bout  (f32)
  gemm_mfma<<<(NQ / 128) * 2, 256, 0, stream>>>(out2, WoT, bout, nullptr, out, 0);
}

// Round 6
// 102.335 us; speedup vs baseline: 1.7211x; 1.0568x over previous
//
#include <hip/hip_runtime.h>
#include <hip/hip_bf16.h>
#include <stdint.h>

// Problem constants (fixed by the reference)
#define NQ    32768
#define NKV   32768
#define CDIM  256
#define NHEADS 8
#define NPTS  4
// Ch = 32, pairs (h,p) = 32, loc cols used = even cols only (x coord)

using bf16x8 = __attribute__((ext_vector_type(8))) short;
using f32x4  = __attribute__((ext_vector_type(4))) float;
using u16x8  = __attribute__((ext_vector_type(8))) ushort;

static __device__ __forceinline__ ushort f2bf(float f) {
  uint32_t u = __float_as_uint(f);
  return (ushort)((u + 0x7FFFu + ((u >> 16) & 1u)) >> 16);  // RNE
}
static __device__ __forceinline__ float bf2f(ushort h) {
  return __uint_as_float(((uint32_t)h) << 16);
}
static __device__ __forceinline__ void async16(const void* g, void* l) {
  __builtin_amdgcn_global_load_lds(
      (const __attribute__((address_space(1))) uint32_t*)g,
      (__attribute__((address_space(3))) uint32_t*)l, 16, 0, 0);
}
#define WAIT_VM(N) do { asm volatile("s_waitcnt vmcnt(" #N ")" ::: "memory"); \
                        __builtin_amdgcn_sched_barrier(0); } while (0)

// K0b: W [256][256] f32 -> W^T [256][256] bf16 (row j holds column j of W,
// k-contiguous — the layout the MFMA B-operand wants).
__global__ __launch_bounds__(256) void transpose_w(const float* __restrict__ W,
                                                   ushort* __restrict__ WT) {
  int j = blockIdx.x, k = threadIdx.x;
  WT[j * 256 + k] = f2bf(W[k * 256 + j]);
}

// ---------------------------------------------------------------------------
// K3: bf16 MFMA GEMM  C[M,256] = A[M,256] * B + bias   (A already bf16)
__global__ __launch_bounds__(256) void gemm_mfma(
    const ushort* __restrict__ A, const ushort* __restrict__ BT,
    const float* __restrict__ bias, ushort* __restrict__ Cb,
    float* __restrict__ Cf, int out_bf16) {
  __shared__ ushort Alds[128 * 32];
  __shared__ ushort Blds[128 * 32];
  const int t = threadIdx.x;
  const int wave = t >> 6, lane = t & 63;
  const int mt = blockIdx.x >> 1, nt = blockIdx.x & 1;
  const int m0 = mt * 128, n0 = nt * 128;
  const int wr = wave >> 1, wc = wave & 1;
  const int r16 = lane & 15, kb = (lane >> 4) * 8;

  f32x4 acc[4][4] = {};

  for (int kt = 0; kt < 256; kt += 32) {
    __syncthreads();
#pragma unroll
    for (int it = 0; it < 2; ++it) {
      int c = it * 256 + t;
      int row = c >> 2, cc = c & 3;
      async16(A  + ((size_t)(m0 + row) * 256 + kt + cc * 8),
              Alds + (size_t)(it * 256 + wave * 64) * 8);
      async16(BT + ((size_t)(n0 + row) * 256 + kt + cc * 8),
              Blds + (size_t)(it * 256 + wave * 64) * 8);
    }
    __syncthreads();

    bf16x8 af[4], bfr[4];
#pragma unroll
    for (int m = 0; m < 4; ++m)
      af[m] = *(const bf16x8*)&Alds[(wr * 64 + m * 16 + r16) * 32 + kb];
#pragma unroll
    for (int n = 0; n < 4; ++n)
      bfr[n] = *(const bf16x8*)&Blds[(wc * 64 + n * 16 + r16) * 32 + kb];
#pragma unroll
    for (int m = 0; m < 4; ++m)
#pragma unroll
      for (int n = 0; n < 4; ++n)
        acc[m][n] = __builtin_amdgcn_mfma_f32_16x16x32_bf16(af[m], bfr[n],
                                                            acc[m][n], 0, 0, 0);
  }

  const int rg = lane >> 4;
#pragma unroll
  for (int m = 0; m < 4; ++m)
#pragma unroll
    for (int n = 0; n < 4; ++n) {
      int gc = n0 + wc * 64 + n * 16 + r16;
      float bb = bias[gc];
#pragma unroll
      for (int r = 0; r < 4; ++r) {
        int gr = m0 + wr * 64 + m * 16 + rg * 4 + r;
        float v = acc[m][n][r] + bb;
        if (out_bf16) Cb[(size_t)gr * 256 + gc] = f2bf(v);
        else          Cf[(size_t)gr * 256 + gc] = v;
      }
    }
}

// K1: same GEMM but A is f32 (value matrix) — converted to bf16 in-register
// during staging (fuses the old convert_val pass; saves 48MB HBM + a launch).
__global__ __launch_bounds__(256) void gemm_mfma_fa(
    const float* __restrict__ Af, const ushort* __restrict__ BT,
    const float* __restrict__ bias, ushort* __restrict__ Cb) {
  __shared__ ushort Alds[128 * 32];
  __shared__ ushort Blds[128 * 32];
  const int t = threadIdx.x;
  const int wave = t >> 6, lane = t & 63;
  const int mt = blockIdx.x >> 1, nt = blockIdx.x & 1;
  const int m0 = mt * 128, n0 = nt * 128;
  const int wr = wave >> 1, wc = wave & 1;
  const int r16 = lane & 15, kb = (lane >> 4) * 8;

  f32x4 acc[4][4] = {};

  for (int kt = 0; kt < 256; kt += 32) {
    __syncthreads();
#pragma unroll
    for (int it = 0; it < 2; ++it) {  // B via global_load_lds (bf16 already)
      int c = it * 256 + t;
      int row = c >> 2, cc = c & 3;
      async16(BT + ((size_t)(n0 + row) * 256 + kt + cc * 8),
              Blds + (size_t)(it * 256 + wave * 64) * 8);
    }
#pragma unroll
    for (int it = 0; it < 2; ++it) {  // A: f32 -> reg -> bf16 -> ds_write
      int c = it * 256 + t;
      int row = c >> 2, cc = c & 3;
      const float* src = Af + (size_t)(m0 + row) * 256 + kt + cc * 8;
      f32x4 a = *(const f32x4*)src;
      f32x4 b = *(const f32x4*)(src + 4);
      u16x8 w;
#pragma unroll
      for (int e = 0; e < 4; ++e) { w[e] = f2bf(a[e]); w[4 + e] = f2bf(b[e]); }
      *(u16x8*)&Alds[(size_t)c * 8] = w;   // c*8 == row*32 + cc*8
    }
    __syncthreads();  // covers vmcnt (B) + lgkm (A ds_write)

    bf16x8 af[4], bfr[4];
#pragma unroll
    for (int m = 0; m < 4; ++m)
      af[m] = *(const bf16x8*)&Alds[(wr * 64 + m * 16 + r16) * 32 + kb];
#pragma unroll
    for (int n = 0; n < 4; ++n)
      bfr[n] = *(const bf16x8*)&Blds[(wc * 64 + n * 16 + r16) * 32 + kb];
#pragma unroll
    for (int m = 0; m < 4; ++m)
#pragma unroll
      for (int n = 0; n < 4; ++n)
        acc[m][n] = __builtin_amdgcn_mfma_f32_16x16x32_bf16(af[m], bfr[n],
                                                            acc[m][n], 0, 0, 0);
  }

  const int rg = lane >> 4;
#pragma unroll
  for (int m = 0; m < 4; ++m)
#pragma unroll
    for (int n = 0; n < 4; ++n) {
      int gc = n0 + wc * 64 + n * 16 + r16;
      float bb = bias[gc];
#pragma unroll
      for (int r = 0; r < 4; ++r) {
        int gr = m0 + wr * 64 + m * 16 + rg * 4 + r;
        Cb[(size_t)gr * 256 + gc] = f2bf(acc[m][n][r] + bb);
      }
    }
}

// ---------------------------------------------------------------------------
// K2a: loc_raw[N,64] = query @ [Wr_even | Wo_even]   (fp32 score path).
__global__ __launch_bounds__(256) void loc_gemm(const float* __restrict__ Q,
                                                const float* __restrict__ Wr,
                                                const float* __restrict__ Wo,
                                                float* __restrict__ locr) {
  __shared__ float AT[64][68];
  __shared__ float Bl[64][64];
  const int m0 = blockIdx.x * 64;
  const int t = threadIdx.x;
  const int tr = t >> 4, tc = t & 15;
  float acc[4][4] = {};

  for (int k0 = 0; k0 < 256; k0 += 64) {
    __syncthreads();
#pragma unroll
    for (int i = 0; i < 4; ++i) {
      int row = (t >> 4) + 16 * i;
      int kk = (t & 15) * 4;
      float4 v = *(const float4*)&Q[(size_t)(m0 + row) * 256 + k0 + kk];
      AT[kk + 0][row] = v.x; AT[kk + 1][row] = v.y;
      AT[kk + 2][row] = v.z; AT[kk + 3][row] = v.w;
    }
#pragma unroll
    for (int i = 0; i < 16; ++i) {
      int j = t & 63;
      int kk = (t >> 6) + 4 * i;
      float v = (j < 32) ? Wr[(size_t)(k0 + kk) * 64 + 2 * j]
                         : Wo[(size_t)(k0 + kk) * 64 + 2 * (j - 32)];
      Bl[kk][j] = v;
    }
    __syncthreads();
#pragma unroll 8
    for (int kk = 0; kk < 64; ++kk) {
      float4 a = *(const float4*)&AT[kk][tr * 4];
      float4 b = *(const float4*)&Bl[kk][tc * 4];
      float av[4] = {a.x, a.y, a.z, a.w};
      float bv4[4] = {b.x, b.y, b.z, b.w};
#pragma unroll
      for (int i = 0; i < 4; ++i)
#pragma unroll
        for (int jj = 0; jj < 4; ++jj) acc[i][jj] += av[i] * bv4[jj];
    }
  }
#pragma unroll
  for (int i = 0; i < 4; ++i)
#pragma unroll
    for (int jj = 0; jj < 4; ++jj)
      locr[(size_t)(m0 + tr * 4 + i) * 64 + tc * 4 + jj] = acc[i][jj];
}

// ---------------------------------------------------------------------------
// K2b: fused sampling + attention. Wave = 1 query row. LDS-staged gathers,
// line-efficient (1 TA lookup per 128B line) AND single-round-trip: q(1KB) +
// k0|k1(8KB) + v0|v1(4KB) live in SEPARATE per-wave LDS regions, so all 13
// global_load_lds issue back-to-back with no intermediate vmcnt(0)
// (r4's phase-reuse serialized 3 round trips; r5's reg-gathers cost 11x the
// TA lookups). XOR chunk-swizzles are applied on the GLOBAL source (LDS dest
// must stay linear) and chosen so every read-back phase is bank-balanced.
//  k slice s (s<32: k0 of pt=s, s>=32: k1): slot(s,j) holds chunk j^(s&7).
//  v slice sv (pt + 32*r):                  slot(sv,j) holds chunk j^(sv&3)^((sv>>2)&3).
//  q slot (h,j) holds chunk j^h.
__global__ __launch_bounds__(256) void sample_attn(
    const float* __restrict__ query, const float* __restrict__ key,
    const ushort* __restrict__ vtab, const float* __restrict__ locr,
    const float* __restrict__ br, const float* __restrict__ bo,
    ushort* __restrict__ out2) {
  __shared__ char smem[4][13312];           // 8KB k + 4KB v + 1KB q per wave
  const int wave = threadIdx.x >> 6, l = threadIdx.x & 63;
  const int j = l & 31;                     // point id  (dup in both halves)
  const int n = blockIdx.x * 4 + wave;
  const int Mm1 = NKV - 1;
  char* kbuf = smem[wave];
  char* vbuf = kbuf + 8192;
  char* qbuf = kbuf + 12288;

  // sampling location for point j (duplicated across lane halves)
  float rr = locr[(size_t)n * 64 + j];
  float oo = locr[(size_t)n * 64 + 32 + j];
  float ref = 1.0f / (1.0f + expf(-(rr + br[2 * j])));
  float x = (ref + (oo + bo[2 * j])) * (float)Mm1;
  float xf = floorf(x);
  int x0 = (int)fminf(fmaxf(xf, 0.0f), (float)Mm1);
  int x1 = (x0 + 1 > Mm1) ? Mm1 : x0 + 1;
  float wx = x - (float)x0;
  float w0 = 1.0f - wx;

  // ---- stage q: slot l -> (hq=l>>3, cq=l&7) holds chunk cq^hq of head hq
  {
    int hq = l >> 3, cq = l & 7;
    async16(query + (size_t)n * 256 + hq * 32 + ((cq ^ hq) << 2), qbuf);
  }
  // ---- stage k: 8 instrs; instr i covers slices i*8..i*8+8 (slice = pt + 32*(k1))
  {
    int ptg = l >> 3, s7 = l & 7;
    int kch = s7 ^ ptg;                    // chunk fetched (slice&7 == ptg)
#pragma unroll
    for (int i = 0; i < 8; ++i) {
      int pt = ((i & 3) << 3) + ptg;
      int row = (i < 4) ? __shfl(x0, pt, 64) : __shfl(x1, pt, 64);
      int hs = pt >> 2;
      async16(key + (size_t)row * 256 + hs * 32 + (kch << 2), kbuf + i * 1024);
    }
  }
  // ---- stage v: 4 instrs; instr i covers slices i*16..i*16+16
  {
    int cg = (l & 3) ^ ((l >> 2) & 3) ^ ((l >> 4) & 3);  // i-independent
#pragma unroll
    for (int i = 0; i < 4; ++i) {
      int pt = ((i & 1) << 4) + (l >> 2);
      int row = (i < 2) ? __shfl(x0, pt, 64) : __shfl(x1, pt, 64);
      int hp = pt >> 2;
      async16(vtab + (size_t)row * 256 + hp * 32 + cg * 8, vbuf + i * 1024);
    }
  }

  WAIT_VM(4);  // q + k landed (v's 4 still in flight)

  // ---- score: lane (which=l>>5, pt=l&31) computes q . k_which[pt]
  float dot = 0.f;
  {
    int h = (l & 31) >> 2;
#pragma unroll
    for (int c = 0; c < 8; ++c) {
      f32x4 qc = *(const f32x4*)(qbuf + ((h << 3) + (c ^ h)) * 16);
      f32x4 kc = *(const f32x4*)(kbuf + l * 128 + ((c ^ (l & 7)) << 4));
#pragma unroll
      for (int e = 0; e < 4; ++e) dot += qc[e] * kc[e];
    }
  }
  float other = __shfl_xor(dot, 32, 64);
  float d0 = (l < 32) ? dot : other;
  float d1 = (l < 32) ? other : dot;
  float score = (w0 * d0 + wx * d1) * 0.17677669529663687f;  // 1/sqrt(32)

  // softmax over the 4 points of the head (quad lanes, same in both halves)
  float m1 = fmaxf(score, __shfl_xor(score, 1, 64));
  float mx = fmaxf(m1, __shfl_xor(m1, 2, 64));
  float e0 = expf(score - mx);
  float s1 = e0 + __shfl_xor(e0, 1, 64);
  float ssum = s1 + __shfl_xor(s1, 2, 64);
  float attn = e0 / ssum;
  float c0 = attn * w0, c1 = attn * wx;

  // ---- output: lane (h=l>>3, s=l&7) owns channels [s*4, s*4+4) of head h
  const int oh = l >> 3, os = l & 7;
  float cc0[4], cc1[4];
#pragma unroll
  for (int m = 0; m < 4; ++m) {
    cc0[m] = __shfl(c0, oh * 4 + m, 64);
    cc1[m] = __shfl(c1, oh * 4 + m, 64);
  }

  WAIT_VM(0);  // v landed

  float acc[4] = {};
#pragma unroll
  for (int m = 0; m < 4; ++m) {
    int pt = oh * 4 + m;
    int slot = (os >> 1) ^ m ^ (oh & 3);        // ^ (sv&3) ^ ((sv>>2)&3)
    int off = slot * 16 + (os & 1) * 8;
    ushort4 v0 = *(const ushort4*)(vbuf + pt * 64 + off);
    ushort4 v1 = *(const ushort4*)(vbuf + (pt + 32) * 64 + off);
#pragma unroll
    for (int e = 0; e < 4; ++e) {
      float ve0 = bf2f((&v0.x)[e]), ve1 = bf2f((&v1.x)[e]);
      acc[e] += cc0[m] * ve0 + cc1[m] * ve1;
    }
  }
  ushort4 ow;
#pragma unroll
  for (int e = 0; e < 4; ++e) (&ow.x)[e] = f2bf(acc[e]);
  *(ushort4*)(out2 + (size_t)n * 256 + oh * 32 + os * 4) = ow;
}

// ---------------------------------------------------------------------------
extern "C" void kernel_launch(void* const* d_in, const int* in_sizes, int n_in,
                              void* d_out, int out_size, void* d_ws, size_t ws_size,
                              hipStream_t stream) {
  const float* query = (const float*)d_in[0];
  const float* key   = (const float*)d_in[1];
  const float* value = (const float*)d_in[2];
  const float* Wr    = (const float*)d_in[3];
  const float* br    = (const float*)d_in[4];
  const float* Wo    = (const float*)d_in[5];
  const float* bo    = (const float*)d_in[6];
  const float* Wv    = (const float*)d_in[7];
  const float* bv    = (const float*)d_in[8];
  const float* Wout  = (const float*)d_in[9];
  const float* bout  = (const float*)d_in[10];
  float* out = (float*)d_out;

  char* ws = (char*)d_ws;
  ushort* out2  = (ushort*)(ws);                         // 16 MB
  ushort* vtab  = (ushort*)(ws + (16u << 20));           // 16 MB
  float*  locr  = (float*) (ws + (32u << 20));           //  8 MB
  ushort* WvT   = (ushort*)(ws + (40u << 20));           // 128 KB
  ushort* WoT   = (ushort*)(ws + (40u << 20) + (1u << 17));

  transpose_w<<<256, 256, 0, stream>>>(Wv, WvT);
  transpose_w<<<256, 256, 0, stream>>>(Wout, WoT);
  // vtab = bf16(value @ Wv + bv)  (A converted f32->bf16 during staging)
  gemm_mfma_fa<<<(NQ / 128) * 2, 256, 0, stream>>>(value, WvT, bv, vtab);
  // loc_raw = query @ [Wr_even | Wo_even]  (fp32)
  loc_gemm<<<NQ / 64, 256, 0, stream>>>(query, Wr, Wo, locr);
  // fused sampling/attention -> out2 (bf16)
  sample_attn<<<NQ / 4, 256, 0, stream>>>(query, key, vtab, locr, br, bo, out2);
  // out = out2 @ Wout + bout  (f32)
  gemm_mfma<<<(NQ / 128) * 2, 256, 0, stream>>>(out2, WoT, bout, nullptr, out, 0);
}

// Round 7
// 100.941 us; speedup vs baseline: 1.7448x; 1.0138x over previous
//
#include <hip/hip_runtime.h>
#include <hip/hip_bf16.h>
#include <stdint.h>

// Problem constants (fixed by the reference)
#define NQ    32768
#define NKV   32768
#define CDIM  256
#define NHEADS 8
#define NPTS  4
// Ch = 32, pairs (h,p) = 32, loc cols used = even cols only (x coord)

using bf16x8 = __attribute__((ext_vector_type(8))) short;
using f32x4  = __attribute__((ext_vector_type(4))) float;
using u16x8  = __attribute__((ext_vector_type(8))) ushort;

static __device__ __forceinline__ ushort f2bf(float f) {
  uint32_t u = __float_as_uint(f);
  return (ushort)((u + 0x7FFFu + ((u >> 16) & 1u)) >> 16);  // RNE
}
static __device__ __forceinline__ float bf2f(ushort h) {
  return __uint_as_float(((uint32_t)h) << 16);
}
static __device__ __forceinline__ void async16(const void* g, void* l) {
  __builtin_amdgcn_global_load_lds(
      (const __attribute__((address_space(1))) uint32_t*)g,
      (__attribute__((address_space(3))) uint32_t*)l, 16, 0, 0);
}
#define WAIT_VM(N) do { asm volatile("s_waitcnt vmcnt(" #N ")" ::: "memory"); \
                        __builtin_amdgcn_sched_barrier(0); } while (0)

// K0b: W [256][256] f32 -> W^T [256][256] bf16 (row j holds column j of W,
// k-contiguous — the layout the MFMA B-operand wants).
__global__ __launch_bounds__(256) void transpose_w(const float* __restrict__ W,
                                                   ushort* __restrict__ WT) {
  int j = blockIdx.x, k = threadIdx.x;
  WT[j * 256 + k] = f2bf(W[k * 256 + j]);
}

// ---------------------------------------------------------------------------
// K3: bf16 MFMA GEMM  C[M,256] = A[M,256] * B + bias   (A already bf16)
__global__ __launch_bounds__(256) void gemm_mfma(
    const ushort* __restrict__ A, const ushort* __restrict__ BT,
    const float* __restrict__ bias, ushort* __restrict__ Cb,
    float* __restrict__ Cf, int out_bf16) {
  __shared__ ushort Alds[128 * 32];
  __shared__ ushort Blds[128 * 32];
  const int t = threadIdx.x;
  const int wave = t >> 6, lane = t & 63;
  const int mt = blockIdx.x >> 1, nt = blockIdx.x & 1;
  const int m0 = mt * 128, n0 = nt * 128;
  const int wr = wave >> 1, wc = wave & 1;
  const int r16 = lane & 15, kb = (lane >> 4) * 8;

  f32x4 acc[4][4] = {};

  for (int kt = 0; kt < 256; kt += 32) {
    __syncthreads();
#pragma unroll
    for (int it = 0; it < 2; ++it) {
      int c = it * 256 + t;
      int row = c >> 2, cc = c & 3;
      async16(A  + ((size_t)(m0 + row) * 256 + kt + cc * 8),
              Alds + (size_t)(it * 256 + wave * 64) * 8);
      async16(BT + ((size_t)(n0 + row) * 256 + kt + cc * 8),
              Blds + (size_t)(it * 256 + wave * 64) * 8);
    }
    __syncthreads();

    bf16x8 af[4], bfr[4];
#pragma unroll
    for (int m = 0; m < 4; ++m)
      af[m] = *(const bf16x8*)&Alds[(wr * 64 + m * 16 + r16) * 32 + kb];
#pragma unroll
    for (int n = 0; n < 4; ++n)
      bfr[n] = *(const bf16x8*)&Blds[(wc * 64 + n * 16 + r16) * 32 + kb];
#pragma unroll
    for (int m = 0; m < 4; ++m)
#pragma unroll
      for (int n = 0; n < 4; ++n)
        acc[m][n] = __builtin_amdgcn_mfma_f32_16x16x32_bf16(af[m], bfr[n],
                                                            acc[m][n], 0, 0, 0);
  }

  const int rg = lane >> 4;
#pragma unroll
  for (int m = 0; m < 4; ++m)
#pragma unroll
    for (int n = 0; n < 4; ++n) {
      int gc = n0 + wc * 64 + n * 16 + r16;
      float bb = bias[gc];
#pragma unroll
      for (int r = 0; r < 4; ++r) {
        int gr = m0 + wr * 64 + m * 16 + rg * 4 + r;
        float v = acc[m][n][r] + bb;
        if (out_bf16) Cb[(size_t)gr * 256 + gc] = f2bf(v);
        else          Cf[(size_t)gr * 256 + gc] = v;
      }
    }
}

// K1: value GEMM. A is f32 (converted to bf16 in-register during staging —
// fuses the old convert_val pass) and C is written TRANSPOSED to
// vtabT[H][M][Ch] so sample_attn's (x0,x0+1) value pair is one contiguous
// 128B region (avg 1.5 cache lines instead of 2).
__global__ __launch_bounds__(256) void gemm_mfma_fa(
    const float* __restrict__ Af, const ushort* __restrict__ BT,
    const float* __restrict__ bias, ushort* __restrict__ CbT) {
  __shared__ ushort Alds[128 * 32];
  __shared__ ushort Blds[128 * 32];
  const int t = threadIdx.x;
  const int wave = t >> 6, lane = t & 63;
  const int mt = blockIdx.x >> 1, nt = blockIdx.x & 1;
  const int m0 = mt * 128, n0 = nt * 128;
  const int wr = wave >> 1, wc = wave & 1;
  const int r16 = lane & 15, kb = (lane >> 4) * 8;

  f32x4 acc[4][4] = {};

  for (int kt = 0; kt < 256; kt += 32) {
    __syncthreads();
#pragma unroll
    for (int it = 0; it < 2; ++it) {  // B via global_load_lds (bf16 already)
      int c = it * 256 + t;
      int row = c >> 2, cc = c & 3;
      async16(BT + ((size_t)(n0 + row) * 256 + kt + cc * 8),
              Blds + (size_t)(it * 256 + wave * 64) * 8);
    }
#pragma unroll
    for (int it = 0; it < 2; ++it) {  // A: f32 -> reg -> bf16 -> ds_write
      int c = it * 256 + t;
      int row = c >> 2, cc = c & 3;
      const float* src = Af + (size_t)(m0 + row) * 256 + kt + cc * 8;
      f32x4 a = *(const f32x4*)src;
      f32x4 b = *(const f32x4*)(src + 4);
      u16x8 w;
#pragma unroll
      for (int e = 0; e < 4; ++e) { w[e] = f2bf(a[e]); w[4 + e] = f2bf(b[e]); }
      *(u16x8*)&Alds[(size_t)c * 8] = w;   // c*8 == row*32 + cc*8
    }
    __syncthreads();  // covers vmcnt (B) + lgkm (A ds_write)

    bf16x8 af[4], bfr[4];
#pragma unroll
    for (int m = 0; m < 4; ++m)
      af[m] = *(const bf16x8*)&Alds[(wr * 64 + m * 16 + r16) * 32 + kb];
#pragma unroll
    for (int n = 0; n < 4; ++n)
      bfr[n] = *(const bf16x8*)&Blds[(wc * 64 + n * 16 + r16) * 32 + kb];
#pragma unroll
    for (int m = 0; m < 4; ++m)
#pragma unroll
      for (int n = 0; n < 4; ++n)
        acc[m][n] = __builtin_amdgcn_mfma_f32_16x16x32_bf16(af[m], bfr[n],
                                                            acc[m][n], 0, 0, 0);
  }

  const int rg = lane >> 4;
#pragma unroll
  for (int m = 0; m < 4; ++m)
#pragma unroll
    for (int n = 0; n < 4; ++n) {
      int gc = n0 + wc * 64 + n * 16 + r16;   // h = gc>>5, ch = gc&31
      float bb = bias[gc];
#pragma unroll
      for (int r = 0; r < 4; ++r) {
        int gr = m0 + wr * 64 + m * 16 + rg * 4 + r;
        CbT[((size_t)(gc >> 5) * NKV + gr) * 32 + (gc & 31)] =
            f2bf(acc[m][n][r] + bb);
      }
    }
}

// ---------------------------------------------------------------------------
// K2a: loc_raw[N,64] = query @ [Wr_even | Wo_even]   (fp32 score path).
__global__ __launch_bounds__(256) void loc_gemm(const float* __restrict__ Q,
                                                const float* __restrict__ Wr,
                                                const float* __restrict__ Wo,
                                                float* __restrict__ locr) {
  __shared__ float AT[64][68];
  __shared__ float Bl[64][64];
  const int m0 = blockIdx.x * 64;
  const int t = threadIdx.x;
  const int tr = t >> 4, tc = t & 15;
  float acc[4][4] = {};

  for (int k0 = 0; k0 < 256; k0 += 64) {
    __syncthreads();
#pragma unroll
    for (int i = 0; i < 4; ++i) {
      int row = (t >> 4) + 16 * i;
      int kk = (t & 15) * 4;
      float4 v = *(const float4*)&Q[(size_t)(m0 + row) * 256 + k0 + kk];
      AT[kk + 0][row] = v.x; AT[kk + 1][row] = v.y;
      AT[kk + 2][row] = v.z; AT[kk + 3][row] = v.w;
    }
#pragma unroll
    for (int i = 0; i < 16; ++i) {
      int j = t & 63;
      int kk = (t >> 6) + 4 * i;
      float v = (j < 32) ? Wr[(size_t)(k0 + kk) * 64 + 2 * j]
                         : Wo[(size_t)(k0 + kk) * 64 + 2 * (j - 32)];
      Bl[kk][j] = v;
    }
    __syncthreads();
#pragma unroll 8
    for (int kk = 0; kk < 64; ++kk) {
      float4 a = *(const float4*)&AT[kk][tr * 4];
      float4 b = *(const float4*)&Bl[kk][tc * 4];
      float av[4] = {a.x, a.y, a.z, a.w};
      float bv4[4] = {b.x, b.y, b.z, b.w};
#pragma unroll
      for (int i = 0; i < 4; ++i)
#pragma unroll
        for (int jj = 0; jj < 4; ++jj) acc[i][jj] += av[i] * bv4[jj];
    }
  }
#pragma unroll
  for (int i = 0; i < 4; ++i)
#pragma unroll
    for (int jj = 0; jj < 4; ++jj)
      locr[(size_t)(m0 + tr * 4 + i) * 64 + tc * 4 + jj] = acc[i][jj];
}

// ---------------------------------------------------------------------------
// K2b: fused sampling + attention. Wave = 1 query row; lane owns one
// (which, point) for the score and one (head, ch-group) for the output.
// Single memory round-trip: q (per-lane regs, L1-broadcast) + k slices
// (8KB LDS) + v pairs (4KB LDS, from vtabT so x0/x0+1 are contiguous) all
// issue back-to-back; score waits vmcnt(4), v-combine waits vmcnt(0).
// Bank-conflict-free swizzles (verified per 8-lane service group):
//  k slot s (s<32: k0 of pt=s; else k1): pos p holds chunk p^(s&7)^((s>>3)&3)
//  v pair pt (128B = rows x0,x0+1 of head pt>>2): pos p holds chunk p^(pt&7)
__global__ __launch_bounds__(256) void sample_attn(
    const float* __restrict__ query, const float* __restrict__ key,
    const ushort* __restrict__ vtabT, const float* __restrict__ locr,
    const float* __restrict__ br, const float* __restrict__ bo,
    ushort* __restrict__ out2) {
  __shared__ char smem[4][12288];           // 8KB k + 4KB v per wave
  const int wave = threadIdx.x >> 6, l = threadIdx.x & 63;
  const int j = l & 31;                     // point id (dup in both halves)
  const int n = blockIdx.x * 4 + wave;
  const int Mm1 = NKV - 1;
  char* kbuf = smem[wave];
  char* vbuf = kbuf + 8192;

  // sampling location for point j
  float rr = locr[(size_t)n * 64 + j];
  float oo = locr[(size_t)n * 64 + 32 + j];
  float ref = 1.0f / (1.0f + expf(-(rr + br[2 * j])));
  float x = (ref + (oo + bo[2 * j])) * (float)Mm1;
  float xf = floorf(x);
  int x0 = (int)fminf(fmaxf(xf, 0.0f), (float)Mm1);
  int x1 = (x0 + 1 > Mm1) ? Mm1 : x0 + 1;
  float wx = x - (float)x0;
  float w0 = 1.0f - wx;

  // ---- q per-lane (issued first; quad lanes share addresses -> L1 bcast)
  const float* qr = query + (size_t)n * 256 + (j >> 2) * 32;
  f32x4 qv[8];
#pragma unroll
  for (int c = 0; c < 8; ++c) qv[c] = *(const f32x4*)(qr + c * 4);
  __builtin_amdgcn_sched_barrier(0);

  // ---- stage k: 8 instrs; instr i covers slots i*8..i*8+7
  {
    const int ptg = l >> 3, p7 = l & 7;
#pragma unroll
    for (int i = 0; i < 8; ++i) {
      int pt = ((i & 3) << 3) + ptg;
      int row = (i < 4) ? __shfl(x0, pt, 64) : __shfl(x1, pt, 64);
      int sc = p7 ^ ptg ^ (i & 3);
      async16(key + (size_t)row * 256 + (pt >> 2) * 32 + (sc << 2),
              kbuf + i * 1024);
    }
  }
  __builtin_amdgcn_sched_barrier(0);
  // ---- stage v pairs: 4 instrs; instr i covers pairs i*8..i*8+7
  {
    const int pg3 = l >> 3, c7 = l & 7;
    const int sc = c7 ^ pg3;               // pg&7 == pg3
#pragma unroll
    for (int i = 0; i < 4; ++i) {
      int pg = i * 8 + pg3;
      int row = __shfl(x0, pg, 64);
      async16(vtabT + ((size_t)(pg >> 2) * NKV + row) * 32 + sc * 8,
              vbuf + i * 1024);
    }
  }
  __builtin_amdgcn_sched_barrier(0);

  WAIT_VM(4);  // q + k landed (4 v loads still in flight)

  // ---- score: lane l = (which=l>>5, pt=l&31) computes q . k_which[pt]
  float dot = 0.f;
#pragma unroll
  for (int c = 0; c < 8; ++c) {
    int pos = c ^ (l & 7) ^ ((l >> 3) & 3);
    f32x4 kc = *(const f32x4*)(kbuf + l * 128 + pos * 16);
#pragma unroll
    for (int e = 0; e < 4; ++e) dot += qv[c][e] * kc[e];
  }
  float other = __shfl_xor(dot, 32, 64);
  float d0 = (l < 32) ? dot : other;
  float d1 = (l < 32) ? other : dot;
  float score = (w0 * d0 + wx * d1) * 0.17677669529663687f;  // 1/sqrt(32)

  // softmax over the head's 4 points (quad lanes; same in both halves)
  float m1 = fmaxf(score, __shfl_xor(score, 1, 64));
  float mx = fmaxf(m1, __shfl_xor(m1, 2, 64));
  float e0 = expf(score - mx);
  float s1 = e0 + __shfl_xor(e0, 1, 64);
  float ssum = s1 + __shfl_xor(s1, 2, 64);
  float attn = e0 / ssum;
  // v-pair block holds rows [x0, x0+1]; when x0==M-1 its 2nd half is garbage
  // but the reference value is v[x0] exactly (g0==g1): fold w0+wx=1 into c0.
  int edge = (x0 == Mm1);
  float c1v = edge ? 0.0f : attn * wx;
  float c0v = edge ? attn * (w0 + wx) : attn * w0;

  // ---- output: lane (oh=l>>3, os=l&7) owns channels [os*4, os*4+4) of oh
  const int oh = l >> 3, os = l & 7;
  float cc0[4], cc1[4];
#pragma unroll
  for (int m = 0; m < 4; ++m) {
    cc0[m] = __shfl(c0v, oh * 4 + m, 64);
    cc1[m] = __shfl(c1v, oh * 4 + m, 64);
  }

  WAIT_VM(0);  // v landed

  float acc[4] = {};
#pragma unroll
  for (int m = 0; m < 4; ++m) {
    int pt = oh * 4 + m;
    int pos0 = (os >> 1) ^ (pt & 7);        // row x0, chunk os>>1
    int pos1 = (4 + (os >> 1)) ^ (pt & 7);  // row x0+1
    const char* pb = vbuf + pt * 128 + (os & 1) * 8;
    ushort4 v0 = *(const ushort4*)(pb + pos0 * 16);
    ushort4 v1 = *(const ushort4*)(pb + pos1 * 16);
#pragma unroll
    for (int e = 0; e < 4; ++e)
      acc[e] += cc0[m] * bf2f((&v0.x)[e]) + cc1[m] * bf2f((&v1.x)[e]);
  }
  ushort4 ow;
#pragma unroll
  for (int e = 0; e < 4; ++e) (&ow.x)[e] = f2bf(acc[e]);
  *(ushort4*)(out2 + (size_t)n * 256 + oh * 32 + os * 4) = ow;
}

// ---------------------------------------------------------------------------
extern "C" void kernel_launch(void* const* d_in, const int* in_sizes, int n_in,
                              void* d_out, int out_size, void* d_ws, size_t ws_size,
                              hipStream_t stream) {
  const float* query = (const float*)d_in[0];
  const float* key   = (const float*)d_in[1];
  const float* value = (const float*)d_in[2];
  const float* Wr    = (const float*)d_in[3];
  const float* br    = (const float*)d_in[4];
  const float* Wo    = (const float*)d_in[5];
  const float* bo    = (const float*)d_in[6];
  const float* Wv    = (const float*)d_in[7];
  const float* bv    = (const float*)d_in[8];
  const float* Wout  = (const float*)d_in[9];
  const float* bout  = (const float*)d_in[10];
  float* out = (float*)d_out;

  char* ws = (char*)d_ws;
  ushort* out2  = (ushort*)(ws);                         // 16 MB
  ushort* vtabT = (ushort*)(ws + (16u << 20));           // 16 MB [H][M][Ch]
  float*  locr  = (float*) (ws + (32u << 20));           //  8 MB
  ushort* WvT   = (ushort*)(ws + (40u << 20));           // 128 KB
  ushort* WoT   = (ushort*)(ws + (40u << 20) + (1u << 17));

  transpose_w<<<256, 256, 0, stream>>>(Wv, WvT);
  transpose_w<<<256, 256, 0, stream>>>(Wout, WoT);
  // vtabT[h][m][ch] = bf16(value @ Wv + bv)  (A f32->bf16 during staging)
  gemm_mfma_fa<<<(NQ / 128) * 2, 256, 0, stream>>>(value, WvT, bv, vtabT);
  // loc_raw = query @ [Wr_even | Wo_even]  (fp32)
  loc_gemm<<<NQ / 64, 256, 0, stream>>>(query, Wr, Wo, locr);
  // fused sampling/attention -> out2 (bf16)
  sample_attn<<<NQ / 4, 256, 0, stream>>>(query, key, vtabT, locr, br, bo, out2);
  // out = out2 @ Wout + bout  (f32)
  gemm_mfma<<<(NQ / 128) * 2, 256, 0, stream>>>(out2, WoT, bout, nullptr, out, 0);
}